// Round 6
// baseline (690.981 us; speedup 1.0000x reference)
//
#include <hip/hip_runtime.h>

// SPADE ResNet block — bf16 MFMA implicit-GEMM, LDS-free direct-load version.
// B=4, FIN=64, FOUT=32, FMID=32, NCLS=4, NH=64, S=32 (S3=32768).
//
// Round-6 change: conv_mfma no longer stages input tiles in LDS (staging +
// barriers cost ~= MFMA time and the data is L2-resident anyway). B-fragments
// are loaded directly from global xt[vox][ci] at per-tap compile-time offsets
// with boundary masking. No __shared__, no __syncthreads in the conv kernel.

#define S3 32768
constexpr float EPS = 1e-5f;

typedef __attribute__((ext_vector_type(8))) short s16x8;
typedef __attribute__((ext_vector_type(4))) float f32x4;
typedef __attribute__((ext_vector_type(4))) unsigned short u16x4;
typedef __attribute__((ext_vector_type(8))) unsigned short u16x8;

__device__ __forceinline__ float bf2f(unsigned short u) {
  union { unsigned int i; float f; } v; v.i = ((unsigned int)u) << 16; return v.f;
}
__device__ __forceinline__ unsigned short f2bf(float f) {
  union { float f; unsigned int i; } v; v.f = f;
  unsigned int r = (v.i + 0x7FFFu + ((v.i >> 16) & 1u)) >> 16;
  return (unsigned short)r;
}

// ---------------------------------------------------------------- stats ----
// One block per (b, c): mean + rstd over 32768 voxels of fp32 planar input.
__global__ __launch_bounds__(256) void stats_kernel(const float* __restrict__ x,
                                                    float* __restrict__ mu,
                                                    float* __restrict__ rstd) {
  const int bc = blockIdx.x;
  const float* p = x + (size_t)bc * S3;
  float s = 0.f, s2 = 0.f;
  for (int i = threadIdx.x; i < S3 / 4; i += 256) {
    float4 v = reinterpret_cast<const float4*>(p)[i];
    s  += v.x + v.y + v.z + v.w;
    s2 += v.x * v.x + v.y * v.y + v.z * v.z + v.w * v.w;
  }
  for (int off = 32; off; off >>= 1) {
    s  += __shfl_down(s, off, 64);
    s2 += __shfl_down(s2, off, 64);
  }
  __shared__ float ls[4], ls2[4];
  const int wid = threadIdx.x >> 6;
  if ((threadIdx.x & 63) == 0) { ls[wid] = s; ls2[wid] = s2; }
  __syncthreads();
  if (threadIdx.x == 0) {
    float S = 0.f, S2 = 0.f;
    for (int i = 0; i < 4; ++i) { S += ls[i]; S2 += ls2[i]; }
    const float m = S / (float)S3;
    const float var = S2 / (float)S3 - m * m;
    mu[bc] = m;
    rstd[bc] = rsqrtf(var + EPS);
  }
}

// Stats over bf16 T-layout tensor [B][S3][32] (dx0), phase 1.
__global__ __launch_bounds__(256) void stats_t32_p1(const short* __restrict__ t,
                                                    float* __restrict__ part) {
  const int b = blockIdx.y;
  const int chunk = blockIdx.x;
  const int tid = threadIdx.x;
  const int pq = tid & 3;
  float s[8], s2[8];
#pragma unroll
  for (int j = 0; j < 8; ++j) { s[j] = 0.f; s2[j] = 0.f; }
  const int vbase = chunk * 512;
#pragma unroll
  for (int v = tid >> 2; v < 512; v += 64) {
    u16x8 u = *reinterpret_cast<const u16x8*>(
        &t[((size_t)b * S3 + vbase + v) * 32 + pq * 8]);
#pragma unroll
    for (int j = 0; j < 8; ++j) { float f = bf2f(u[j]); s[j] += f; s2[j] += f * f; }
  }
#pragma unroll
  for (int off = 4; off < 64; off <<= 1) {
#pragma unroll
    for (int j = 0; j < 8; ++j) {
      s[j]  += __shfl_xor(s[j], off, 64);
      s2[j] += __shfl_xor(s2[j], off, 64);
    }
  }
  __shared__ float red[4][4][16];
  const int wv = tid >> 6, lane = tid & 63;
  if (lane < 4) {
#pragma unroll
    for (int j = 0; j < 8; ++j) { red[wv][lane][j] = s[j]; red[wv][lane][8 + j] = s2[j]; }
  }
  __syncthreads();
  if (tid < 32) {
    const int p = tid >> 3, j = tid & 7;
    float S = 0.f, S2 = 0.f;
#pragma unroll
    for (int w = 0; w < 4; ++w) { S += red[w][p][j]; S2 += red[w][p][8 + j]; }
    const int c = p * 8 + j;
    part[((size_t)(b * 64 + chunk)) * 64 + c] = S;
    part[((size_t)(b * 64 + chunk)) * 64 + 32 + c] = S2;
  }
}

// phase 2: fold 64 partials -> mu/rstd. One block, 128 threads (b = t>>5).
__global__ __launch_bounds__(128) void stats_t32_p2(const float* __restrict__ part,
                                                    float* __restrict__ mu,
                                                    float* __restrict__ rstd) {
  const int tid = threadIdx.x;
  const int b = tid >> 5, c = tid & 31;
  float S = 0.f, S2 = 0.f;
#pragma unroll 4
  for (int k = 0; k < 64; ++k) {
    S  += part[((size_t)(b * 64 + k)) * 64 + c];
    S2 += part[((size_t)(b * 64 + k)) * 64 + 32 + c];
  }
  const float m = S / (float)S3;
  const float var = S2 / (float)S3 - m * m;
  mu[b * 32 + c] = m;
  rstd[b * 32 + c] = rsqrtf(var + EPS);
}

// ------------------------------------------------------------ transpose ----
// x [B][64][S3] fp32 -> xt [B][S3][64] bf16.
__global__ __launch_bounds__(256) void transpose_x(const float* __restrict__ x,
                                                   short* __restrict__ xt) {
  const int b = blockIdx.y;
  const int v0 = blockIdx.x * 64;
  __shared__ unsigned short t[64][72];
  const int vox = threadIdx.x & 63;
  const int cg = threadIdx.x >> 6;
#pragma unroll
  for (int k = 0; k < 16; ++k) {
    const int ci = cg * 16 + k;
    t[vox][ci] = f2bf(x[((size_t)(b * 64 + ci)) * S3 + v0 + vox]);
  }
  __syncthreads();
  const int vv = threadIdx.x >> 2, part = threadIdx.x & 3;
  uint4 u0 = *reinterpret_cast<const uint4*>(&t[vv][part * 16]);
  uint4 u1 = *reinterpret_cast<const uint4*>(&t[vv][part * 16 + 8]);
  short* dst = &xt[((size_t)(b * S3 + v0 + vv)) * 64 + part * 16];
  *reinterpret_cast<uint4*>(dst) = u0;
  *reinterpret_cast<uint4*>(dst + 8) = u1;
}

// --------------------------------------------------------------- repack ----
// fp32 [cls][CO_src][CI][27] -> bf16 [b][27][KC][CO2][32].
// paired=0: channel co comes from wA channel co.
// paired=1: chunks of CBLK = [gamma half | beta half]; gamma ch from wA,
//           beta ch from wB, both at channel blk*(CBLK/2) + (co%CBLK)%H.
__global__ __launch_bounds__(256) void repack_w(
    const float* __restrict__ wA, const float* __restrict__ wB,
    short* __restrict__ dst, const int* __restrict__ y,
    int CBLK, int CO2, int CI, long clsA, long clsB, int paired, int total) {
  const int b = blockIdx.y;
  const int idx = blockIdx.x * 256 + threadIdx.x;
  if (idx >= total) return;
  const int cls = y[b];
  const int KC = CI / 32;
  const int ci = idx & 31;
  const int co = (idx >> 5) % CO2;
  const int rest = idx / (32 * CO2);
  const int kc = rest % KC;
  const int tap = rest / KC;
  float v;
  if (paired) {
    const int H = CBLK >> 1;
    const int blk = co / CBLK, w = co % CBLK;
    if (w < H)
      v = wA[(size_t)clsA * cls + ((size_t)(blk * H + w) * CI + kc * 32 + ci) * 27 + tap];
    else
      v = wB[(size_t)clsB * cls + ((size_t)(blk * H + w - H) * CI + kc * 32 + ci) * 27 + tap];
  } else {
    v = wA[(size_t)clsA * cls + ((size_t)co * CI + kc * 32 + ci) * 27 + tap];
  }
  dst[(((size_t)(b * 27 + tap) * KC + kc) * CO2 + co) * 32 + ci] = (short)f2bf(v);
}

// ------------------------------------------------------------ conv MFMA ----
// LDS-free: B-fragments read directly from global xt with per-tap offsets and
// boundary masks. Block = 4x8x8 spatial tile (wave = one d-slice, 4 voxel
// groups of 16), CBLK output channels at co_base = blockIdx.z*CBLK.
// EPI: 0 relu+bias -> bf16 T   1 bias -> bf16 T
//      2 SPADE (norm input bf16 T, stride NNORM) + lrelu -> bf16 T
//      4 bias + accumulate into fp32 planar out
template <int CIN, int CBLK, int COTOT, int EPI, int NNORM>
__global__ __launch_bounds__(256, (CBLK >= 64) ? 3 : 4) void conv_mfma(
    const short* __restrict__ xt,      // [B][S3][CIN] bf16
    const short* __restrict__ W,       // [B][27][KC][COTOT][32] bf16
    const float* __restrict__ bias,    // EPI 0/1/4
    int bias_stride,
    const int* __restrict__ y,
    const short* __restrict__ xnb,     // EPI2: bf16 T [B][S3][NNORM]
    const float* __restrict__ mu,
    const float* __restrict__ rstd,
    const float* __restrict__ bgs,     // [NCLS][NNORM]
    const float* __restrict__ bbs,
    float* __restrict__ outf,          // EPI4
    short* __restrict__ outb) {        // EPI 0..2
  constexpr int KC = CIN / 32;
  constexpr int NCOG = CBLK / 16;
  const int tid = threadIdx.x;
  const int b = blockIdx.y;
  const int cls = y[b];
  const int co_base = blockIdx.z * CBLK;
  const int tile = blockIdx.x;
  const int d0 = (tile >> 4) * 4, h0 = ((tile >> 2) & 3) * 8, w0 = (tile & 3) * 8;
  const int lane = tid & 63, wid = tid >> 6;
  const int kq = lane >> 4, l15 = lane & 15;
  const int dh = (lane >> 3) & 1, wv = lane & 7;

  const int vd = d0 + wid;           // wave-uniform d
  const int vh = h0 + dh;            // + 2*vg per voxel group
  const int vw = w0 + wv;

  f32x4 acc[4][NCOG];
  const f32x4 z4 = {0.f, 0.f, 0.f, 0.f};
#pragma unroll
  for (int v = 0; v < 4; ++v)
#pragma unroll
    for (int c = 0; c < NCOG; ++c) acc[v][c] = z4;

  const short* xb = xt + ((size_t)b * S3 + vd * 1024 + vh * 32 + vw) * CIN + kq * 8;

  for (int kc = 0; kc < KC; ++kc) {
#pragma unroll
    for (int kd = 0; kd < 3; ++kd) {
      const bool okd = (unsigned)(vd + kd - 1) < 32u;
#pragma unroll
      for (int kh = 0; kh < 3; ++kh) {
#pragma unroll
        for (int kw = 0; kw < 3; ++kw) {
          const bool okw = (unsigned)(vw + kw - 1) < 32u;
          const long doff = (long)((kd - 1) * 1024 + (kh - 1) * 32 + (kw - 1)) * CIN;
          s16x8 bf[4];
#pragma unroll
          for (int vg = 0; vg < 4; ++vg) {
            const bool ok = okd & okw & ((unsigned)(vh + 2 * vg + kh - 1) < 32u);
            s16x8 v = {0, 0, 0, 0, 0, 0, 0, 0};
            if (ok)
              v = *reinterpret_cast<const s16x8*>(
                  xb + doff + (long)vg * (64 * CIN) + kc * 32);
            bf[vg] = v;
          }
          const int tap = kd * 9 + kh * 3 + kw;
          const short* wt =
              W + (((size_t)(b * 27 + tap) * KC + kc) * COTOT + co_base) * 32;
#pragma unroll
          for (int cog = 0; cog < NCOG; ++cog) {
            s16x8 af = *reinterpret_cast<const s16x8*>(&wt[(cog * 16 + l15) * 32 + kq * 8]);
#pragma unroll
            for (int vg = 0; vg < 4; ++vg)
              acc[vg][cog] =
                  __builtin_amdgcn_mfma_f32_16x16x32_bf16(af, bf[vg], acc[vg][cog], 0, 0, 0);
          }
        }
      }
    }
  }

  // epilogue. C-frag: col = lane&15 -> voxel, row = kq*4 + r -> co (within cog).
  const int gv = vd * 1024 + vh * 32 + vw;   // vg adds vg*64

  if constexpr (EPI == 0 || EPI == 1) {
#pragma unroll
    for (int cog = 0; cog < NCOG; ++cog) {
      const int c0 = co_base + cog * 16 + kq * 4;
      const f32x4 b4 = *reinterpret_cast<const f32x4*>(&bias[cls * bias_stride + c0]);
#pragma unroll
      for (int vg = 0; vg < 4; ++vg) {
        u16x4 o;
#pragma unroll
        for (int r = 0; r < 4; ++r) {
          float v = acc[vg][cog][r] + b4[r];
          if constexpr (EPI == 0) v = fmaxf(v, 0.f);
          o[r] = f2bf(v);
        }
        *reinterpret_cast<u16x4*>(&outb[((size_t)b * S3 + gv + vg * 64) * COTOT + c0]) = o;
      }
    }
  }

  if constexpr (EPI == 2) {
    constexpr int NG = NCOG / 2;       // gamma cogs; beta at cog+NG
    const int nb = blockIdx.z * (CBLK / 2);
#pragma unroll
    for (int cog = 0; cog < NG; ++cog) {
      const int c0 = nb + cog * 16 + kq * 4;
      const f32x4 m4  = *reinterpret_cast<const f32x4*>(&mu[b * NNORM + c0]);
      const f32x4 r4  = *reinterpret_cast<const f32x4*>(&rstd[b * NNORM + c0]);
      const f32x4 g4  = *reinterpret_cast<const f32x4*>(&bgs[cls * NNORM + c0]);
      const f32x4 bb4 = *reinterpret_cast<const f32x4*>(&bbs[cls * NNORM + c0]);
#pragma unroll
      for (int vg = 0; vg < 4; ++vg) {
        const size_t vgl = (size_t)b * S3 + gv + vg * 64;
        u16x4 u = *reinterpret_cast<const u16x4*>(&xnb[vgl * NNORM + c0]);
        u16x4 o;
#pragma unroll
        for (int r = 0; r < 4; ++r) {
          const float gamma = acc[vg][cog][r] + g4[r];
          const float beta  = acc[vg][cog + NG][r] + bb4[r];
          const float nrm = (bf2f(u[r]) - m4[r]) * r4[r];
          float h = nrm * (1.f + gamma) + beta;
          h = h > 0.f ? h : 0.2f * h;
          o[r] = f2bf(h);
        }
        *reinterpret_cast<u16x4*>(&outb[vgl * NNORM + c0]) = o;
      }
    }
  }

  if constexpr (EPI == 4) {
#pragma unroll
    for (int cog = 0; cog < NCOG; ++cog) {
      const int c0 = co_base + cog * 16 + kq * 4;
      const f32x4 b4 = *reinterpret_cast<const f32x4*>(&bias[c0]);
#pragma unroll
      for (int vg = 0; vg < 4; ++vg) {
#pragma unroll
        for (int r = 0; r < 4; ++r) {
          float* p = &outf[((size_t)(b * 32 + c0 + r)) * S3 + gv + vg * 64];
          *p += acc[vg][cog][r] + b4[r];
        }
      }
    }
  }
}

// ------------------------------------------------------------- shortcut ----
// 1x1x1 conv 64 -> 32, no bias, fp32 planar. Initializes d_out.
__global__ __launch_bounds__(256) void shortcut_kernel(const float* __restrict__ x,
                                                       const float* __restrict__ wsc,
                                                       float* __restrict__ out) {
  const int b = blockIdx.y;
  const int v = blockIdx.x * 256 + threadIdx.x;
  __shared__ float lw[64 * 32];  // [ci][oc]
  for (int i = threadIdx.x; i < 2048; i += 256) {
    int ci = i >> 5, o = i & 31;
    lw[i] = wsc[o * 64 + ci];
  }
  __syncthreads();
  float acc[32];
#pragma unroll
  for (int o = 0; o < 32; ++o) acc[o] = 0.f;
  const float* xp = x + (size_t)b * 64 * S3 + v;
#pragma unroll 1
  for (int ci = 0; ci < 64; ++ci) {
    const float xv = xp[(size_t)ci * S3];
    const float4* wp = reinterpret_cast<const float4*>(&lw[ci << 5]);
#pragma unroll
    for (int o4 = 0; o4 < 8; ++o4) {
      float4 w4 = wp[o4];
      acc[o4 * 4 + 0] += xv * w4.x;
      acc[o4 * 4 + 1] += xv * w4.y;
      acc[o4 * 4 + 2] += xv * w4.z;
      acc[o4 * 4 + 3] += xv * w4.w;
    }
  }
  float* op = out + (size_t)b * 32 * S3 + v;
#pragma unroll
  for (int o = 0; o < 32; ++o) op[(size_t)o * S3] = acc[o];
}

// ---------------------------------------------------------------- launch ---
extern "C" void kernel_launch(void* const* d_in, const int* in_sizes, int n_in,
                              void* d_out, int out_size, void* d_ws, size_t ws_size,
                              hipStream_t stream) {
  const float* x       = (const float*)d_in[0];
  const int*   y       = (const int*)d_in[1];
  const float* s0_ws   = (const float*)d_in[2];
  const float* s0_bs   = (const float*)d_in[3];
  const float* s0_wg   = (const float*)d_in[4];
  const float* s0_bg   = (const float*)d_in[5];
  const float* s0_wb   = (const float*)d_in[6];
  const float* s0_bb   = (const float*)d_in[7];
  const float* s1_ws   = (const float*)d_in[8];
  const float* s1_bs   = (const float*)d_in[9];
  const float* s1_wg   = (const float*)d_in[10];
  const float* s1_bg   = (const float*)d_in[11];
  const float* s1_wb   = (const float*)d_in[12];
  const float* s1_bb   = (const float*)d_in[13];
  const float* conv0_w = (const float*)d_in[14];
  const float* conv0_b = (const float*)d_in[15];
  const float* conv1_w = (const float*)d_in[16];
  const float* conv1_b = (const float*)d_in[17];
  const float* convs_w = (const float*)d_in[18];

  float* out = (float*)d_out;
  char* ws = (char*)d_ws;
  short* xt    = (short*)(ws);               // [4][S3][64] bf16  16.78 MB
  short* actvT = (short*)(ws + 16777216);    // [4][S3][64]       16.78 MB
  short* hT    = (short*)(ws + 33554432);    // [4][S3][<=64]     16.78 MB
  short* d0T   = (short*)(ws + 50331648);    // [4][S3][32]        8.39 MB
  short* Wa0   = (short*)(ws + 58720256);
  short* Ws0   = (short*)(ws + 60817408);
  short* Wc0   = (short*)(ws + 62914560);
  short* Wa1   = (short*)(ws + 65011712);
  short* Ws1   = (short*)(ws + 67108864);
  short* Wc1   = (short*)(ws + 69206016);
  float* stats = (float*)(ws + 71303168);
  float* mu0 = stats, *rstd0 = stats + 256, *mu1 = stats + 512, *rstd1 = stats + 640;
  float* spart = stats + 1024;               // [4][64][64] partials (16K floats)

  // input transpose + instance-norm stats of x
  transpose_x<<<dim3(512, 4), 256, 0, stream>>>(x, xt);
  stats_kernel<<<dim3(256), 256, 0, stream>>>(x, mu0, rstd0);

  // weight repacks (per-b class selected), bf16
  repack_w<<<dim3(432, 4), 256, 0, stream>>>(s0_ws, nullptr, Wa0, y, 32, 64, 64,
                                             64L * 64 * 27, 0, 0, 110592);
  repack_w<<<dim3(864, 4), 256, 0, stream>>>(s0_wg, s0_wb, Ws0, y, 64, 128, 64,
                                             64L * 64 * 27, 64L * 64 * 27, 1, 221184);
  repack_w<<<dim3(216, 4), 256, 0, stream>>>(conv0_w, nullptr, Wc0, y, 32, 32, 64,
                                             0, 0, 0, 55296);
  repack_w<<<dim3(216, 4), 256, 0, stream>>>(s1_ws, nullptr, Wa1, y, 32, 64, 32,
                                             64L * 32 * 27, 0, 0, 55296);
  repack_w<<<dim3(432, 4), 256, 0, stream>>>(s1_wg, s1_wb, Ws1, y, 32, 64, 64,
                                             32L * 64 * 27, 32L * 64 * 27, 1, 110592);
  repack_w<<<dim3(108, 4), 256, 0, stream>>>(conv1_w, nullptr, Wc1, y, 32, 32, 32,
                                             0, 0, 0, 27648);

  // actv0 = relu(conv3(x, s0_ws) + s0_bs)          [B][S3][64]
  conv_mfma<64, 32, 64, 0, 0><<<dim3(128, 4, 2), 256, 0, stream>>>(
      xt, Wa0, s0_bs, 64, y, nullptr, nullptr, nullptr, nullptr, nullptr,
      nullptr, actvT);
  // h0 = lrelu(SPADE0(x; actv0))                   [B][S3][64]
  conv_mfma<64, 64, 128, 2, 64><<<dim3(128, 4, 2), 256, 0, stream>>>(
      actvT, Ws0, nullptr, 0, y, xt, mu0, rstd0, s0_bg, s0_bb,
      nullptr, hT);
  // dx0 = conv3(h0, conv0_w) + conv0_b             [B][S3][32]
  conv_mfma<64, 32, 32, 1, 0><<<dim3(128, 4, 1), 256, 0, stream>>>(
      hT, Wc0, conv0_b, 0, y, nullptr, nullptr, nullptr, nullptr, nullptr,
      nullptr, d0T);
  // instance-norm stats of dx0 (two-phase)
  stats_t32_p1<<<dim3(64, 4), 256, 0, stream>>>(d0T, spart);
  stats_t32_p2<<<dim3(1), 128, 0, stream>>>(spart, mu1, rstd1);
  // actv1 = relu(conv3(dx0, s1_ws) + s1_bs)        [B][S3][64]
  conv_mfma<32, 32, 64, 0, 0><<<dim3(128, 4, 2), 256, 0, stream>>>(
      d0T, Wa1, s1_bs, 64, y, nullptr, nullptr, nullptr, nullptr, nullptr,
      nullptr, actvT);
  // h1 = lrelu(SPADE1(dx0; actv1))                 [B][S3][32]
  conv_mfma<64, 32, 64, 2, 32><<<dim3(128, 4, 2), 256, 0, stream>>>(
      actvT, Ws1, nullptr, 0, y, d0T, mu1, rstd1, s1_bg, s1_bb,
      nullptr, hT);
  // out = conv1x1(x, convs_w)
  shortcut_kernel<<<dim3(128, 4), 256, 0, stream>>>(x, convs_w, out);
  // out += conv3(h1, conv1_w) + conv1_b
  conv_mfma<32, 32, 32, 4, 0><<<dim3(128, 4, 1), 256, 0, stream>>>(
      hT, Wc1, conv1_b, 0, y, nullptr, nullptr, nullptr, nullptr, nullptr,
      out, nullptr);
}

// Round 7
// 303.063 us; speedup vs baseline: 2.2800x; 2.2800x over previous
//
#include <hip/hip_runtime.h>

// SPADE ResNet block — bf16 MFMA implicit-GEMM, 32x32x16 MFMA + dual LDS
// staging (weights AND inputs) via global_load_lds with zero-page OOB.
// B=4, FIN=64, FOUT=32, FMID=32, NCLS=4, NH=64, S=32 (S3=32768).
//
// R7: R4/R6 were A-frag-starved (per-tap 16B weight loads from L2, ~4 in
// flight -> MfmaUtil 10-16%). Now: wave tile 64co x 128vox on 32x32x16 MFMA
// (2x FLOP per fragment pair), weights staged in LDS per (k16,kd) chunk,
// inputs staged in LDS per k16, both via global_load_lds(16B) with a zeroed
// 4KB page substituted for OOB/pad lanes. 2 barriers/phase, 12 phases.

#define S3 32768
constexpr float EPS = 1e-5f;

typedef __attribute__((ext_vector_type(8))) short s16x8;
typedef __attribute__((ext_vector_type(4))) float f32x4;
typedef __attribute__((ext_vector_type(16))) float f32x16;
typedef __attribute__((ext_vector_type(4))) unsigned short u16x4;
typedef __attribute__((ext_vector_type(8))) unsigned short u16x8;

#define GLL(g, l)                                                        \
  __builtin_amdgcn_global_load_lds(                                      \
      (const __attribute__((address_space(1))) void*)(g),                \
      (__attribute__((address_space(3))) void*)(l), 16, 0, 0)

__device__ __forceinline__ float bf2f(unsigned short u) {
  union { unsigned int i; float f; } v; v.i = ((unsigned int)u) << 16; return v.f;
}
__device__ __forceinline__ unsigned short f2bf(float f) {
  union { float f; unsigned int i; } v; v.f = f;
  unsigned int r = (v.i + 0x7FFFu + ((v.i >> 16) & 1u)) >> 16;
  return (unsigned short)r;
}

// ---------------------------------------------------------------- stats ----
__global__ __launch_bounds__(256) void stats_kernel(const float* __restrict__ x,
                                                    float* __restrict__ mu,
                                                    float* __restrict__ rstd) {
  const int bc = blockIdx.x;
  const float* p = x + (size_t)bc * S3;
  float s = 0.f, s2 = 0.f;
  for (int i = threadIdx.x; i < S3 / 4; i += 256) {
    float4 v = reinterpret_cast<const float4*>(p)[i];
    s  += v.x + v.y + v.z + v.w;
    s2 += v.x * v.x + v.y * v.y + v.z * v.z + v.w * v.w;
  }
  for (int off = 32; off; off >>= 1) {
    s  += __shfl_down(s, off, 64);
    s2 += __shfl_down(s2, off, 64);
  }
  __shared__ float ls[4], ls2[4];
  const int wid = threadIdx.x >> 6;
  if ((threadIdx.x & 63) == 0) { ls[wid] = s; ls2[wid] = s2; }
  __syncthreads();
  if (threadIdx.x == 0) {
    float S = 0.f, S2 = 0.f;
    for (int i = 0; i < 4; ++i) { S += ls[i]; S2 += ls2[i]; }
    const float m = S / (float)S3;
    const float var = S2 / (float)S3 - m * m;
    mu[bc] = m;
    rstd[bc] = rsqrtf(var + EPS);
  }
}

// Stats over bf16 T-layout tensor [B][S3][32] (dx0), phase 1.
__global__ __launch_bounds__(256) void stats_t32_p1(const short* __restrict__ t,
                                                    float* __restrict__ part) {
  const int b = blockIdx.y;
  const int chunk = blockIdx.x;
  const int tid = threadIdx.x;
  const int pq = tid & 3;
  float s[8], s2[8];
#pragma unroll
  for (int j = 0; j < 8; ++j) { s[j] = 0.f; s2[j] = 0.f; }
  const int vbase = chunk * 512;
#pragma unroll
  for (int v = tid >> 2; v < 512; v += 64) {
    u16x8 u = *reinterpret_cast<const u16x8*>(
        &t[((size_t)b * S3 + vbase + v) * 32 + pq * 8]);
#pragma unroll
    for (int j = 0; j < 8; ++j) { float f = bf2f(u[j]); s[j] += f; s2[j] += f * f; }
  }
#pragma unroll
  for (int off = 4; off < 64; off <<= 1) {
#pragma unroll
    for (int j = 0; j < 8; ++j) {
      s[j]  += __shfl_xor(s[j], off, 64);
      s2[j] += __shfl_xor(s2[j], off, 64);
    }
  }
  __shared__ float red[4][4][16];
  const int wv = tid >> 6, lane = tid & 63;
  if (lane < 4) {
#pragma unroll
    for (int j = 0; j < 8; ++j) { red[wv][lane][j] = s[j]; red[wv][lane][8 + j] = s2[j]; }
  }
  __syncthreads();
  if (tid < 32) {
    const int p = tid >> 3, j = tid & 7;
    float S = 0.f, S2 = 0.f;
#pragma unroll
    for (int w = 0; w < 4; ++w) { S += red[w][p][j]; S2 += red[w][p][8 + j]; }
    const int c = p * 8 + j;
    part[((size_t)(b * 64 + chunk)) * 64 + c] = S;
    part[((size_t)(b * 64 + chunk)) * 64 + 32 + c] = S2;
  }
}

__global__ __launch_bounds__(128) void stats_t32_p2(const float* __restrict__ part,
                                                    float* __restrict__ mu,
                                                    float* __restrict__ rstd) {
  const int tid = threadIdx.x;
  const int b = tid >> 5, c = tid & 31;
  float S = 0.f, S2 = 0.f;
#pragma unroll 4
  for (int k = 0; k < 64; ++k) {
    S  += part[((size_t)(b * 64 + k)) * 64 + c];
    S2 += part[((size_t)(b * 64 + k)) * 64 + 32 + c];
  }
  const float m = S / (float)S3;
  const float var = S2 / (float)S3 - m * m;
  mu[b * 32 + c] = m;
  rstd[b * 32 + c] = rsqrtf(var + EPS);
}

// ------------------------------------------------------------ transpose ----
// x [B][64][S3] fp32 -> xt [B][S3][64] bf16.
__global__ __launch_bounds__(256) void transpose_x(const float* __restrict__ x,
                                                   short* __restrict__ xt) {
  const int b = blockIdx.y;
  const int v0 = blockIdx.x * 64;
  __shared__ unsigned short t[64][72];
  const int vox = threadIdx.x & 63;
  const int cg = threadIdx.x >> 6;
#pragma unroll
  for (int k = 0; k < 16; ++k) {
    const int ci = cg * 16 + k;
    t[vox][ci] = f2bf(x[((size_t)(b * 64 + ci)) * S3 + v0 + vox]);
  }
  __syncthreads();
  const int vv = threadIdx.x >> 2, part = threadIdx.x & 3;
  uint4 u0 = *reinterpret_cast<const uint4*>(&t[vv][part * 16]);
  uint4 u1 = *reinterpret_cast<const uint4*>(&t[vv][part * 16 + 8]);
  short* dst = &xt[((size_t)(b * S3 + v0 + vv)) * 64 + part * 16];
  *reinterpret_cast<uint4*>(dst) = u0;
  *reinterpret_cast<uint4*>(dst + 8) = u1;
}

// --------------------------------------------------------------- repack ----
// fp32 [cls][CO_src][CI][27] -> bf16 [b][27][KCH=CI/16][CO2][16ci].
// paired=1: chunks of CBLK = [gamma half | beta half] of channel range.
__global__ __launch_bounds__(256) void repack_w(
    const float* __restrict__ wA, const float* __restrict__ wB,
    short* __restrict__ dst, const int* __restrict__ y,
    int CBLK, int CO2, int CI, long clsA, long clsB, int paired, int total) {
  const int b = blockIdx.y;
  const int idx = blockIdx.x * 256 + threadIdx.x;
  if (idx >= total) return;
  const int cls = y[b];
  const int KCH = CI / 16;
  const int ci = idx & 15;
  const int co = (idx >> 4) % CO2;
  const int rest = idx / (16 * CO2);
  const int k16 = rest % KCH;
  const int tap = rest / KCH;
  const int srcch = k16 * 16 + ci;
  float v;
  if (paired) {
    const int H = CBLK >> 1;
    const int blk = co / CBLK, w = co % CBLK;
    if (w < H)
      v = wA[(size_t)clsA * cls + ((size_t)(blk * H + w) * CI + srcch) * 27 + tap];
    else
      v = wB[(size_t)clsB * cls + ((size_t)(blk * H + w - H) * CI + srcch) * 27 + tap];
  } else {
    v = wA[(size_t)clsA * cls + ((size_t)co * CI + srcch) * 27 + tap];
  }
  dst[(((size_t)(b * 27 + tap) * KCH + k16) * CO2 + co) * 16 + ci] = (short)f2bf(v);
}

// ------------------------------------------------------------ conv MFMA ----
// 8x8x8 tile, 4 waves x 4 groups of 32 voxels, CBLK co per block (NCOG=CBLK/32
// fragments of 32x32x16). 12 phases = (CIN/16) x 3 kd; weights (9 taps) and
// inputs staged to LDS via global_load_lds; OOB lanes read the zero page.
// EPI: 0 relu+bias->bf16T  1 bias->bf16T  2 SPADE+lrelu->bf16T  4 +=fp32 planar
template <int CIN, int CBLK, int COTOT, int EPI, int NNORM>
__global__ __launch_bounds__(256, 2) void conv_mfma(
    const short* __restrict__ xt,      // [B][S3][CIN] bf16
    const short* __restrict__ W,       // [B][27][KCH][COTOT][16] bf16
    const float* __restrict__ bias,
    int bias_stride,
    const int* __restrict__ y,
    const short* __restrict__ xnb,     // EPI2: bf16 T [B][S3][NNORM]
    const float* __restrict__ mu,
    const float* __restrict__ rstd,
    const float* __restrict__ bgs,     // [NCLS][NNORM]
    const float* __restrict__ bbs,
    const short* __restrict__ zp,      // 4KB zero page
    float* __restrict__ outf,          // EPI4
    short* __restrict__ outb) {        // EPI 0..2
  constexpr int KCH = CIN / 16;
  constexpr int NCOG = CBLK / 32;
  constexpr int WIT = (CBLK == 64) ? 1280 : 768;   // padded 16B weight items
  constexpr int WSH = (CBLK == 64) ? 6 : 5;        // log2(CBLK)

  __shared__ short ldsX[2048 * 8];     // [1024 slots][16 ci] (+pad slots)
  __shared__ short ldsW[WIT * 8];      // [9 taps][CBLK co][16 ci] (+pad)

  const int tid = threadIdx.x;
  const int lane = tid & 63, wid = tid >> 6;
  const int l31 = lane & 31, khf = lane >> 5;
  const int b = blockIdx.y;
  const int cls = y[b];
  const int co_base = blockIdx.z * CBLK;
  const int tile = blockIdx.x;
  const int d0 = (tile >> 4) * 8, h0 = ((tile >> 2) & 3) * 8, w0 = (tile & 3) * 8;

  // per-thread input staging sources (8 x 16B items covering 1024 slots)
  const short* gsrc[8];
#pragma unroll
  for (int k = 0; k < 8; ++k) {
    const int i = tid + k * 256;
    const int slot = i >> 1, half = i & 1;
    const short* g = zp;
    if (slot < 1000) {
      const int pd = slot / 100, r0 = slot - pd * 100;
      const int ph = r0 / 10, pw = r0 - ph * 10;
      const int gd = d0 + pd - 1, gh = h0 + ph - 1, gw = w0 + pw - 1;
      if ((unsigned)gd < 32u && (unsigned)gh < 32u && (unsigned)gw < 32u)
        g = xt + ((size_t)b * S3 + gd * 1024 + gh * 32 + gw) * CIN + half * 8;
    }
    gsrc[k] = g;
  }

  f32x16 acc[4][NCOG];
#pragma unroll
  for (int v = 0; v < 4; ++v)
#pragma unroll
    for (int c = 0; c < NCOG; ++c)
#pragma unroll
      for (int r = 0; r < 16; ++r) acc[v][c][r] = 0.f;

  const int hw = (l31 >> 3) * 10 + (l31 & 7);

#pragma unroll 1
  for (int kc = 0; kc < KCH; ++kc) {
#pragma unroll 1
    for (int kd = 0; kd < 3; ++kd) {
      // stage weights for (kc, kd): 9 taps x CBLK x 16ci
#pragma unroll
      for (int k = 0; k < WIT / 256; ++k) {
        const int i = tid + k * 256;
        const int row = i >> 1, half = i & 1;
        const int t9 = row >> WSH;
        const int co = row & (CBLK - 1);
        const short* g = (t9 < 9)
            ? W + (((size_t)(b * 27 + kd * 9 + t9) * KCH + kc) * COTOT +
                   co_base + co) * 16 + half * 8
            : zp;
        GLL(g, &ldsW[i * 8]);
      }
      if (kd == 0) {
#pragma unroll
        for (int k = 0; k < 8; ++k) {
          const int i = tid + k * 256;
          GLL(gsrc[k] + kc * 16, &ldsX[i * 8]);
        }
      }
      __syncthreads();

#pragma unroll
      for (int kh = 0; kh < 3; ++kh) {
#pragma unroll
        for (int kw = 0; kw < 3; ++kw) {
          s16x8 af[NCOG];
#pragma unroll
          for (int c = 0; c < NCOG; ++c)
            af[c] = *reinterpret_cast<const s16x8*>(
                &ldsW[((kh * 3 + kw) * CBLK + c * 32 + l31) * 16 + khf * 8]);
          s16x8 bf[4];
#pragma unroll
          for (int vg = 0; vg < 4; ++vg) {
            const int slot = (2 * wid + (vg >> 1) + kd) * 100 +
                             ((vg & 1) * 4 + kh) * 10 + kw + hw;
            bf[vg] = *reinterpret_cast<const s16x8*>(&ldsX[slot * 16 + khf * 8]);
          }
#pragma unroll
          for (int c = 0; c < NCOG; ++c)
#pragma unroll
            for (int vg = 0; vg < 4; ++vg)
              acc[vg][c] = __builtin_amdgcn_mfma_f32_32x32x16_bf16(
                  af[c], bf[vg], acc[vg][c], 0, 0, 0);
        }
      }
      __syncthreads();
    }
  }

  // epilogue. C: col = lane&31 -> voxel, row = (reg&3)+8*(reg>>2)+4*khf -> co.
  const int vdb = d0 + 2 * wid;
  const int vhb = h0 + (l31 >> 3);
  const int vwb = w0 + (l31 & 7);

  if constexpr (EPI == 0 || EPI == 1) {
#pragma unroll
    for (int c = 0; c < NCOG; ++c)
#pragma unroll
      for (int q = 0; q < 4; ++q) {
        const int c0 = co_base + c * 32 + q * 8 + khf * 4;
        const f32x4 b4 = *reinterpret_cast<const f32x4*>(&bias[cls * bias_stride + c0]);
#pragma unroll
        for (int vg = 0; vg < 4; ++vg) {
          const int gv = (vdb + (vg >> 1)) * 1024 + (vhb + (vg & 1) * 4) * 32 + vwb;
          u16x4 o;
#pragma unroll
          for (int rr = 0; rr < 4; ++rr) {
            float v = acc[vg][c][q * 4 + rr] + b4[rr];
            if constexpr (EPI == 0) v = fmaxf(v, 0.f);
            o[rr] = f2bf(v);
          }
          *reinterpret_cast<u16x4*>(&outb[((size_t)b * S3 + gv) * COTOT + c0]) = o;
        }
      }
  }

  if constexpr (EPI == 2) {
    // gamma = acc[.][0], beta = acc[.][1]; norm channels nb..nb+31
    const int nb = blockIdx.z * 32;
#pragma unroll
    for (int q = 0; q < 4; ++q) {
      const int c0 = nb + q * 8 + khf * 4;
      const f32x4 m4  = *reinterpret_cast<const f32x4*>(&mu[b * NNORM + c0]);
      const f32x4 r4  = *reinterpret_cast<const f32x4*>(&rstd[b * NNORM + c0]);
      const f32x4 g4  = *reinterpret_cast<const f32x4*>(&bgs[cls * NNORM + c0]);
      const f32x4 bb4 = *reinterpret_cast<const f32x4*>(&bbs[cls * NNORM + c0]);
#pragma unroll
      for (int vg = 0; vg < 4; ++vg) {
        const int gv = (vdb + (vg >> 1)) * 1024 + (vhb + (vg & 1) * 4) * 32 + vwb;
        const size_t vgl = (size_t)b * S3 + gv;
        u16x4 u = *reinterpret_cast<const u16x4*>(&xnb[vgl * NNORM + c0]);
        u16x4 o;
#pragma unroll
        for (int rr = 0; rr < 4; ++rr) {
          const float gamma = acc[vg][0][q * 4 + rr] + g4[rr];
          const float beta  = acc[vg][1][q * 4 + rr] + bb4[rr];
          const float nrm = (bf2f(u[rr]) - m4[rr]) * r4[rr];
          float h = nrm * (1.f + gamma) + beta;
          h = h > 0.f ? h : 0.2f * h;
          o[rr] = f2bf(h);
        }
        *reinterpret_cast<u16x4*>(&outb[vgl * NNORM + c0]) = o;
      }
    }
  }

  if constexpr (EPI == 4) {
#pragma unroll
    for (int q = 0; q < 4; ++q) {
      const int c0 = q * 8 + khf * 4;
      const f32x4 b4 = *reinterpret_cast<const f32x4*>(&bias[c0]);
#pragma unroll
      for (int vg = 0; vg < 4; ++vg) {
        const int gv = (vdb + (vg >> 1)) * 1024 + (vhb + (vg & 1) * 4) * 32 + vwb;
#pragma unroll
        for (int rr = 0; rr < 4; ++rr) {
          float* p = &outf[((size_t)(b * 32 + c0 + rr)) * S3 + gv];
          *p += acc[vg][0][q * 4 + rr] + b4[rr];
        }
      }
    }
  }
}

// ------------------------------------------------------------- shortcut ----
__global__ __launch_bounds__(256) void shortcut_kernel(const float* __restrict__ x,
                                                       const float* __restrict__ wsc,
                                                       float* __restrict__ out) {
  const int b = blockIdx.y;
  const int v = blockIdx.x * 256 + threadIdx.x;
  __shared__ float lw[64 * 32];  // [ci][oc]
  for (int i = threadIdx.x; i < 2048; i += 256) {
    int ci = i >> 5, o = i & 31;
    lw[i] = wsc[o * 64 + ci];
  }
  __syncthreads();
  float acc[32];
#pragma unroll
  for (int o = 0; o < 32; ++o) acc[o] = 0.f;
  const float* xp = x + (size_t)b * 64 * S3 + v;
#pragma unroll 1
  for (int ci = 0; ci < 64; ++ci) {
    const float xv = xp[(size_t)ci * S3];
    const float4* wp = reinterpret_cast<const float4*>(&lw[ci << 5]);
#pragma unroll
    for (int o4 = 0; o4 < 8; ++o4) {
      float4 w4 = wp[o4];
      acc[o4 * 4 + 0] += xv * w4.x;
      acc[o4 * 4 + 1] += xv * w4.y;
      acc[o4 * 4 + 2] += xv * w4.z;
      acc[o4 * 4 + 3] += xv * w4.w;
    }
  }
  float* op = out + (size_t)b * 32 * S3 + v;
#pragma unroll
  for (int o = 0; o < 32; ++o) op[(size_t)o * S3] = acc[o];
}

// ---------------------------------------------------------------- launch ---
extern "C" void kernel_launch(void* const* d_in, const int* in_sizes, int n_in,
                              void* d_out, int out_size, void* d_ws, size_t ws_size,
                              hipStream_t stream) {
  const float* x       = (const float*)d_in[0];
  const int*   y       = (const int*)d_in[1];
  const float* s0_ws   = (const float*)d_in[2];
  const float* s0_bs   = (const float*)d_in[3];
  const float* s0_wg   = (const float*)d_in[4];
  const float* s0_bg   = (const float*)d_in[5];
  const float* s0_wb   = (const float*)d_in[6];
  const float* s0_bb   = (const float*)d_in[7];
  const float* s1_ws   = (const float*)d_in[8];
  const float* s1_bs   = (const float*)d_in[9];
  const float* s1_wg   = (const float*)d_in[10];
  const float* s1_bg   = (const float*)d_in[11];
  const float* s1_wb   = (const float*)d_in[12];
  const float* s1_bb   = (const float*)d_in[13];
  const float* conv0_w = (const float*)d_in[14];
  const float* conv0_b = (const float*)d_in[15];
  const float* conv1_w = (const float*)d_in[16];
  const float* conv1_b = (const float*)d_in[17];
  const float* convs_w = (const float*)d_in[18];

  float* out = (float*)d_out;
  char* ws = (char*)d_ws;
  short* xt    = (short*)(ws);               // [4][S3][64] bf16  16.78 MB
  short* actvT = (short*)(ws + 16777216);    // [4][S3][64]       16.78 MB
  short* hT    = (short*)(ws + 33554432);    // [4][S3][<=64]     16.78 MB
  short* d0T   = (short*)(ws + 50331648);    // [4][S3][32]        8.39 MB
  short* Wa0   = (short*)(ws + 58720256);
  short* Ws0   = (short*)(ws + 60817408);
  short* Wc0   = (short*)(ws + 62914560);
  short* Wa1   = (short*)(ws + 65011712);
  short* Ws1   = (short*)(ws + 67108864);
  short* Wc1   = (short*)(ws + 69206016);
  short* zp    = (short*)(ws + 70254592);    // 4KB zero page
  float* stats = (float*)(ws + 71303168);
  float* mu0 = stats, *rstd0 = stats + 256, *mu1 = stats + 512, *rstd1 = stats + 640;
  float* spart = stats + 1024;               // [4][64][64] partials

  hipMemsetAsync(zp, 0, 4096, stream);

  transpose_x<<<dim3(512, 4), 256, 0, stream>>>(x, xt);
  stats_kernel<<<dim3(256), 256, 0, stream>>>(x, mu0, rstd0);

  // weight repacks (per-b class selected) -> [b][27][KCH][CO2][16]
  repack_w<<<dim3(432, 4), 256, 0, stream>>>(s0_ws, nullptr, Wa0, y, 64, 64, 64,
                                             64L * 64 * 27, 0, 0, 110592);
  repack_w<<<dim3(864, 4), 256, 0, stream>>>(s0_wg, s0_wb, Ws0, y, 64, 128, 64,
                                             64L * 64 * 27, 64L * 64 * 27, 1, 221184);
  repack_w<<<dim3(216, 4), 256, 0, stream>>>(conv0_w, nullptr, Wc0, y, 32, 32, 64,
                                             0, 0, 0, 55296);
  repack_w<<<dim3(216, 4), 256, 0, stream>>>(s1_ws, nullptr, Wa1, y, 64, 64, 32,
                                             64L * 32 * 27, 0, 0, 55296);
  repack_w<<<dim3(432, 4), 256, 0, stream>>>(s1_wg, s1_wb, Ws1, y, 64, 64, 64,
                                             32L * 64 * 27, 32L * 64 * 27, 1, 110592);
  repack_w<<<dim3(108, 4), 256, 0, stream>>>(conv1_w, nullptr, Wc1, y, 32, 32, 32,
                                             0, 0, 0, 27648);

  // actv0 = relu(conv3(x, s0_ws) + s0_bs)          [B][S3][64]
  conv_mfma<64, 64, 64, 0, 0><<<dim3(64, 4, 1), 256, 0, stream>>>(
      xt, Wa0, s0_bs, 64, y, nullptr, nullptr, nullptr, nullptr, nullptr, zp,
      nullptr, actvT);
  // h0 = lrelu(SPADE0(x; actv0))                   [B][S3][64]
  conv_mfma<64, 64, 128, 2, 64><<<dim3(64, 4, 2), 256, 0, stream>>>(
      actvT, Ws0, nullptr, 0, y, xt, mu0, rstd0, s0_bg, s0_bb, zp,
      nullptr, hT);
  // dx0 = conv3(h0, conv0_w) + conv0_b             [B][S3][32]
  conv_mfma<64, 32, 32, 1, 0><<<dim3(64, 4, 1), 256, 0, stream>>>(
      hT, Wc0, conv0_b, 0, y, nullptr, nullptr, nullptr, nullptr, nullptr, zp,
      nullptr, d0T);
  // instance-norm stats of dx0 (two-phase)
  stats_t32_p1<<<dim3(64, 4), 256, 0, stream>>>(d0T, spart);
  stats_t32_p2<<<dim3(1), 128, 0, stream>>>(spart, mu1, rstd1);
  // actv1 = relu(conv3(dx0, s1_ws) + s1_bs)        [B][S3][64]
  conv_mfma<32, 64, 64, 0, 0><<<dim3(64, 4, 1), 256, 0, stream>>>(
      d0T, Wa1, s1_bs, 64, y, nullptr, nullptr, nullptr, nullptr, nullptr, zp,
      nullptr, actvT);
  // h1 = lrelu(SPADE1(dx0; actv1))                 [B][S3][32]
  conv_mfma<64, 64, 64, 2, 32><<<dim3(64, 4, 1), 256, 0, stream>>>(
      actvT, Ws1, nullptr, 0, y, d0T, mu1, rstd1, s1_bg, s1_bb, zp,
      nullptr, hT);
  // out = conv1x1(x, convs_w)
  shortcut_kernel<<<dim3(128, 4), 256, 0, stream>>>(x, convs_w, out);
  // out += conv3(h1, conv1_w) + conv1_b
  conv_mfma<32, 32, 32, 4, 0><<<dim3(64, 4, 1), 256, 0, stream>>>(
      hT, Wc1, conv1_b, 0, y, nullptr, nullptr, nullptr, nullptr, nullptr, zp,
      out, nullptr);
}

// Round 8
// 301.777 us; speedup vs baseline: 2.2897x; 1.0043x over previous
//
#include <hip/hip_runtime.h>

// SPADE ResNet block — bf16 MFMA implicit-GEMM, 32x32x16 MFMA.
// R8: single-barrier double-buffered pipeline (stage next phase before
// computing current; one __syncthreads per phase) + 4x8x8 tiles so every
// conv dispatch runs >=2 blocks/CU (512-1024 blocks). Wave tile 64co x 64vox.

#define S3 32768
constexpr float EPS = 1e-5f;

typedef __attribute__((ext_vector_type(8))) short s16x8;
typedef __attribute__((ext_vector_type(4))) float f32x4;
typedef __attribute__((ext_vector_type(16))) float f32x16;
typedef __attribute__((ext_vector_type(4))) unsigned short u16x4;
typedef __attribute__((ext_vector_type(8))) unsigned short u16x8;

#define GLL(g, l)                                                        \
  __builtin_amdgcn_global_load_lds(                                      \
      (const __attribute__((address_space(1))) void*)(g),                \
      (__attribute__((address_space(3))) void*)(l), 16, 0, 0)

__device__ __forceinline__ float bf2f(unsigned short u) {
  union { unsigned int i; float f; } v; v.i = ((unsigned int)u) << 16; return v.f;
}
__device__ __forceinline__ unsigned short f2bf(float f) {
  union { float f; unsigned int i; } v; v.f = f;
  unsigned int r = (v.i + 0x7FFFu + ((v.i >> 16) & 1u)) >> 16;
  return (unsigned short)r;
}

// ---------------------------------------------------------------- stats ----
__global__ __launch_bounds__(256) void stats_kernel(const float* __restrict__ x,
                                                    float* __restrict__ mu,
                                                    float* __restrict__ rstd) {
  const int bc = blockIdx.x;
  const float* p = x + (size_t)bc * S3;
  float s = 0.f, s2 = 0.f;
  for (int i = threadIdx.x; i < S3 / 4; i += 256) {
    float4 v = reinterpret_cast<const float4*>(p)[i];
    s  += v.x + v.y + v.z + v.w;
    s2 += v.x * v.x + v.y * v.y + v.z * v.z + v.w * v.w;
  }
  for (int off = 32; off; off >>= 1) {
    s  += __shfl_down(s, off, 64);
    s2 += __shfl_down(s2, off, 64);
  }
  __shared__ float ls[4], ls2[4];
  const int wid = threadIdx.x >> 6;
  if ((threadIdx.x & 63) == 0) { ls[wid] = s; ls2[wid] = s2; }
  __syncthreads();
  if (threadIdx.x == 0) {
    float S = 0.f, S2 = 0.f;
    for (int i = 0; i < 4; ++i) { S += ls[i]; S2 += ls2[i]; }
    const float m = S / (float)S3;
    const float var = S2 / (float)S3 - m * m;
    mu[bc] = m;
    rstd[bc] = rsqrtf(var + EPS);
  }
}

// Stats over bf16 T-layout tensor [B][S3][32] (dx0), phase 1.
__global__ __launch_bounds__(256) void stats_t32_p1(const short* __restrict__ t,
                                                    float* __restrict__ part) {
  const int b = blockIdx.y;
  const int chunk = blockIdx.x;
  const int tid = threadIdx.x;
  const int pq = tid & 3;
  float s[8], s2[8];
#pragma unroll
  for (int j = 0; j < 8; ++j) { s[j] = 0.f; s2[j] = 0.f; }
  const int vbase = chunk * 512;
#pragma unroll
  for (int v = tid >> 2; v < 512; v += 64) {
    u16x8 u = *reinterpret_cast<const u16x8*>(
        &t[((size_t)b * S3 + vbase + v) * 32 + pq * 8]);
#pragma unroll
    for (int j = 0; j < 8; ++j) { float f = bf2f(u[j]); s[j] += f; s2[j] += f * f; }
  }
#pragma unroll
  for (int off = 4; off < 64; off <<= 1) {
#pragma unroll
    for (int j = 0; j < 8; ++j) {
      s[j]  += __shfl_xor(s[j], off, 64);
      s2[j] += __shfl_xor(s2[j], off, 64);
    }
  }
  __shared__ float red[4][4][16];
  const int wv = tid >> 6, lane = tid & 63;
  if (lane < 4) {
#pragma unroll
    for (int j = 0; j < 8; ++j) { red[wv][lane][j] = s[j]; red[wv][lane][8 + j] = s2[j]; }
  }
  __syncthreads();
  if (tid < 32) {
    const int p = tid >> 3, j = tid & 7;
    float S = 0.f, S2 = 0.f;
#pragma unroll
    for (int w = 0; w < 4; ++w) { S += red[w][p][j]; S2 += red[w][p][8 + j]; }
    const int c = p * 8 + j;
    part[((size_t)(b * 64 + chunk)) * 64 + c] = S;
    part[((size_t)(b * 64 + chunk)) * 64 + 32 + c] = S2;
  }
}

__global__ __launch_bounds__(128) void stats_t32_p2(const float* __restrict__ part,
                                                    float* __restrict__ mu,
                                                    float* __restrict__ rstd) {
  const int tid = threadIdx.x;
  const int b = tid >> 5, c = tid & 31;
  float S = 0.f, S2 = 0.f;
#pragma unroll 4
  for (int k = 0; k < 64; ++k) {
    S  += part[((size_t)(b * 64 + k)) * 64 + c];
    S2 += part[((size_t)(b * 64 + k)) * 64 + 32 + c];
  }
  const float m = S / (float)S3;
  const float var = S2 / (float)S3 - m * m;
  mu[b * 32 + c] = m;
  rstd[b * 32 + c] = rsqrtf(var + EPS);
}

// ------------------------------------------------------------ transpose ----
__global__ __launch_bounds__(256) void transpose_x(const float* __restrict__ x,
                                                   short* __restrict__ xt) {
  const int b = blockIdx.y;
  const int v0 = blockIdx.x * 64;
  __shared__ unsigned short t[64][72];
  const int vox = threadIdx.x & 63;
  const int cg = threadIdx.x >> 6;
#pragma unroll
  for (int k = 0; k < 16; ++k) {
    const int ci = cg * 16 + k;
    t[vox][ci] = f2bf(x[((size_t)(b * 64 + ci)) * S3 + v0 + vox]);
  }
  __syncthreads();
  const int vv = threadIdx.x >> 2, part = threadIdx.x & 3;
  uint4 u0 = *reinterpret_cast<const uint4*>(&t[vv][part * 16]);
  uint4 u1 = *reinterpret_cast<const uint4*>(&t[vv][part * 16 + 8]);
  short* dst = &xt[((size_t)(b * S3 + v0 + vv)) * 64 + part * 16];
  *reinterpret_cast<uint4*>(dst) = u0;
  *reinterpret_cast<uint4*>(dst + 8) = u1;
}

// --------------------------------------------------------------- repack ----
// fp32 [cls][CO_src][CI][27] -> bf16 [b][27][KCH=CI/16][CO2][16ci].
__global__ __launch_bounds__(256) void repack_w(
    const float* __restrict__ wA, const float* __restrict__ wB,
    short* __restrict__ dst, const int* __restrict__ y,
    int CBLK, int CO2, int CI, long clsA, long clsB, int paired, int total) {
  const int b = blockIdx.y;
  const int idx = blockIdx.x * 256 + threadIdx.x;
  if (idx >= total) return;
  const int cls = y[b];
  const int KCH = CI / 16;
  const int ci = idx & 15;
  const int co = (idx >> 4) % CO2;
  const int rest = idx / (16 * CO2);
  const int k16 = rest % KCH;
  const int tap = rest / KCH;
  const int srcch = k16 * 16 + ci;
  float v;
  if (paired) {
    const int H = CBLK >> 1;
    const int blk = co / CBLK, w = co % CBLK;
    if (w < H)
      v = wA[(size_t)clsA * cls + ((size_t)(blk * H + w) * CI + srcch) * 27 + tap];
    else
      v = wB[(size_t)clsB * cls + ((size_t)(blk * H + w - H) * CI + srcch) * 27 + tap];
  } else {
    v = wA[(size_t)clsA * cls + ((size_t)co * CI + srcch) * 27 + tap];
  }
  dst[(((size_t)(b * 27 + tap) * KCH + k16) * CO2 + co) * 16 + ci] = (short)f2bf(v);
}

// ------------------------------------------------------------ conv MFMA ----
// 4x8x8 tile (256 vox), 4 waves (wave = d-slice, 64co x 64vox), CBLK co.
// Double-buffered X (6x10x10 halo, per kc) and W (9 taps, per kc,kd);
// one barrier per phase: stage next -> compute current -> barrier.
// EPI: 0 relu+bias->bf16T  1 bias->bf16T  2 SPADE+lrelu->bf16T  4 +=fp32
template <int CIN, int CBLK, int COTOT, int EPI, int NNORM>
__global__ __launch_bounds__(256, 2) void conv_mfma(
    const short* __restrict__ xt,      // [B][S3][CIN] bf16
    const short* __restrict__ W,       // [B][27][KCH][COTOT][16] bf16
    const float* __restrict__ bias,
    int bias_stride,
    const int* __restrict__ y,
    const short* __restrict__ xnb,     // EPI2: bf16 T [B][S3][NNORM]
    const float* __restrict__ mu,
    const float* __restrict__ rstd,
    const float* __restrict__ bgs,     // [NCLS][NNORM]
    const float* __restrict__ bbs,
    const short* __restrict__ zp,      // 4KB zero page
    float* __restrict__ outf,          // EPI4
    short* __restrict__ outb) {        // EPI 0..2
  constexpr int KCH = CIN / 16;
  constexpr int NCOG = CBLK / 32;
  constexpr int WCH = 9 * CBLK * 2;    // weight 16B chunks per phase
  constexpr int WSH = (CBLK == 64) ? 6 : 5;

  __shared__ short ldsX[2][1200 * 8];  // [600 halo slots][16 ci]
  __shared__ short ldsW[2][WCH * 8];   // [9 taps][CBLK co][16 ci]

  const int tid = threadIdx.x;
  const int lane = tid & 63, wid = tid >> 6;
  const int l31 = lane & 31, khf = lane >> 5;
  const int b = blockIdx.y;
  const int cls = y[b];
  const int co_base = blockIdx.z * CBLK;
  const int tile = blockIdx.x;
  const int d0 = (tile >> 4) * 4, h0 = ((tile >> 2) & 3) * 8, w0 = (tile & 3) * 8;

  // X staging sources: 1200 chunks = 600 slots x 2 halves
  const short* gsrc[5];
#pragma unroll
  for (int k = 0; k < 5; ++k) {
    const int i = tid + k * 256;
    const short* g = zp;
    if (i < 1200) {
      const int slot = i >> 1, half = i & 1;
      const int sd = slot / 100, r0 = slot - sd * 100;
      const int sh = r0 / 10, sw = r0 - sh * 10;
      const int gd = d0 + sd - 1, gh = h0 + sh - 1, gw = w0 + sw - 1;
      if ((unsigned)gd < 32u && (unsigned)gh < 32u && (unsigned)gw < 32u)
        g = xt + ((size_t)b * S3 + gd * 1024 + gh * 32 + gw) * CIN + half * 8;
    }
    gsrc[k] = g;
  }

  auto stage_x = [&](int kc, int xb) {
#pragma unroll
    for (int k = 0; k < 5; ++k) {
      const int i = tid + k * 256;
      if (i < 1200) GLL(gsrc[k] + kc * 16, &ldsX[xb][i * 8]);
    }
  };
  auto stage_w = [&](int kc, int kd, int wb) {
#pragma unroll
    for (int k = 0; k < (WCH + 255) / 256; ++k) {
      const int i = tid + k * 256;
      if (i < WCH) {
        const int row = i >> 1, half = i & 1;
        const int t9 = row >> WSH, co = row & (CBLK - 1);
        GLL(W + (((size_t)(b * 27 + kd * 9 + t9) * KCH + kc) * COTOT +
                 co_base + co) * 16 + half * 8,
            &ldsW[wb][i * 8]);
      }
    }
  };

  f32x16 acc[2][NCOG];
#pragma unroll
  for (int v = 0; v < 2; ++v)
#pragma unroll
    for (int c = 0; c < NCOG; ++c)
#pragma unroll
      for (int r = 0; r < 16; ++r) acc[v][c][r] = 0.f;

  const int hwb = ((l31 >> 3) * 10 + (l31 & 7)) * 16 + khf * 8;  // lane base (shorts)

  stage_x(0, 0);
  stage_w(0, 0, 0);
  __syncthreads();

  int xb = 0;
#pragma unroll
  for (int ph = 0; ph < KCH * 3; ++ph) {
    const int kd = ph % 3;
    const int wb = ph & 1;
    if (ph + 1 < KCH * 3) {               // prefetch next phase
      const int nkc = (ph + 1) / 3, nkd = (ph + 1) % 3;
      stage_w(nkc, nkd, wb ^ 1);
      if (nkd == 0) stage_x(nkc, xb ^ 1);
    }
#pragma unroll
    for (int kh = 0; kh < 3; ++kh) {
#pragma unroll
      for (int kw = 0; kw < 3; ++kw) {
        s16x8 af[NCOG];
#pragma unroll
        for (int c = 0; c < NCOG; ++c)
          af[c] = *reinterpret_cast<const s16x8*>(
              &ldsW[wb][((kh * 3 + kw) * CBLK + c * 32 + l31) * 16 + khf * 8]);
        s16x8 bf[2];
#pragma unroll
        for (int vg = 0; vg < 2; ++vg) {
          const int so = ((wid + kd) * 100 + (vg * 4 + kh) * 10 + kw) * 16;
          bf[vg] = *reinterpret_cast<const s16x8*>(&ldsX[xb][so + hwb]);
        }
#pragma unroll
        for (int c = 0; c < NCOG; ++c)
#pragma unroll
          for (int vg = 0; vg < 2; ++vg)
            acc[vg][c] = __builtin_amdgcn_mfma_f32_32x32x16_bf16(
                af[c], bf[vg], acc[vg][c], 0, 0, 0);
      }
    }
    __syncthreads();
    if (kd == 2) xb ^= 1;
  }

  // epilogue. C: col = lane&31 -> voxel, row = (reg&3)+8*(reg>>2)+4*khf -> co.
  const int dgv = (d0 + wid) * 1024 + (h0 + (l31 >> 3)) * 32 + w0 + (l31 & 7);
  // vg adds vg*4 rows of h -> +vg*128

  if constexpr (EPI == 0 || EPI == 1) {
#pragma unroll
    for (int c = 0; c < NCOG; ++c)
#pragma unroll
      for (int q = 0; q < 4; ++q) {
        const int c0 = co_base + c * 32 + q * 8 + khf * 4;
        const f32x4 b4 = *reinterpret_cast<const f32x4*>(&bias[cls * bias_stride + c0]);
#pragma unroll
        for (int vg = 0; vg < 2; ++vg) {
          const int gv = dgv + vg * 128;
          u16x4 o;
#pragma unroll
          for (int rr = 0; rr < 4; ++rr) {
            float v = acc[vg][c][q * 4 + rr] + b4[rr];
            if constexpr (EPI == 0) v = fmaxf(v, 0.f);
            o[rr] = f2bf(v);
          }
          *reinterpret_cast<u16x4*>(&outb[((size_t)b * S3 + gv) * COTOT + c0]) = o;
        }
      }
  }

  if constexpr (EPI == 2) {
    const int nb = blockIdx.z * 32;      // gamma = acc[.][0], beta = acc[.][1]
#pragma unroll
    for (int q = 0; q < 4; ++q) {
      const int c0 = nb + q * 8 + khf * 4;
      const f32x4 m4  = *reinterpret_cast<const f32x4*>(&mu[b * NNORM + c0]);
      const f32x4 r4  = *reinterpret_cast<const f32x4*>(&rstd[b * NNORM + c0]);
      const f32x4 g4  = *reinterpret_cast<const f32x4*>(&bgs[cls * NNORM + c0]);
      const f32x4 bb4 = *reinterpret_cast<const f32x4*>(&bbs[cls * NNORM + c0]);
#pragma unroll
      for (int vg = 0; vg < 2; ++vg) {
        const int gv = dgv + vg * 128;
        const size_t vgl = (size_t)b * S3 + gv;
        u16x4 u = *reinterpret_cast<const u16x4*>(&xnb[vgl * NNORM + c0]);
        u16x4 o;
#pragma unroll
        for (int rr = 0; rr < 4; ++rr) {
          const float gamma = acc[vg][0][q * 4 + rr] + g4[rr];
          const float beta  = acc[vg][1][q * 4 + rr] + bb4[rr];
          const float nrm = (bf2f(u[rr]) - m4[rr]) * r4[rr];
          float h = nrm * (1.f + gamma) + beta;
          h = h > 0.f ? h : 0.2f * h;
          o[rr] = f2bf(h);
        }
        *reinterpret_cast<u16x4*>(&outb[vgl * NNORM + c0]) = o;
      }
    }
  }

  if constexpr (EPI == 4) {
#pragma unroll
    for (int q = 0; q < 4; ++q) {
      const int c0 = q * 8 + khf * 4;
      const f32x4 b4 = *reinterpret_cast<const f32x4*>(&bias[c0]);
#pragma unroll
      for (int vg = 0; vg < 2; ++vg) {
        const int gv = dgv + vg * 128;
#pragma unroll
        for (int rr = 0; rr < 4; ++rr) {
          float* p = &outf[((size_t)(b * 32 + c0 + rr)) * S3 + gv];
          *p += acc[vg][0][q * 4 + rr] + b4[rr];
        }
      }
    }
  }
}

// ------------------------------------------------------------- shortcut ----
__global__ __launch_bounds__(256) void shortcut_kernel(const float* __restrict__ x,
                                                       const float* __restrict__ wsc,
                                                       float* __restrict__ out) {
  const int b = blockIdx.y;
  const int v = blockIdx.x * 256 + threadIdx.x;
  __shared__ float lw[64 * 32];  // [ci][oc]
  for (int i = threadIdx.x; i < 2048; i += 256) {
    int ci = i >> 5, o = i & 31;
    lw[i] = wsc[o * 64 + ci];
  }
  __syncthreads();
  float acc[32];
#pragma unroll
  for (int o = 0; o < 32; ++o) acc[o] = 0.f;
  const float* xp = x + (size_t)b * 64 * S3 + v;
#pragma unroll 1
  for (int ci = 0; ci < 64; ++ci) {
    const float xv = xp[(size_t)ci * S3];
    const float4* wp = reinterpret_cast<const float4*>(&lw[ci << 5]);
#pragma unroll
    for (int o4 = 0; o4 < 8; ++o4) {
      float4 w4 = wp[o4];
      acc[o4 * 4 + 0] += xv * w4.x;
      acc[o4 * 4 + 1] += xv * w4.y;
      acc[o4 * 4 + 2] += xv * w4.z;
      acc[o4 * 4 + 3] += xv * w4.w;
    }
  }
  float* op = out + (size_t)b * 32 * S3 + v;
#pragma unroll
  for (int o = 0; o < 32; ++o) op[(size_t)o * S3] = acc[o];
}

// ---------------------------------------------------------------- launch ---
extern "C" void kernel_launch(void* const* d_in, const int* in_sizes, int n_in,
                              void* d_out, int out_size, void* d_ws, size_t ws_size,
                              hipStream_t stream) {
  const float* x       = (const float*)d_in[0];
  const int*   y       = (const int*)d_in[1];
  const float* s0_ws   = (const float*)d_in[2];
  const float* s0_bs   = (const float*)d_in[3];
  const float* s0_wg   = (const float*)d_in[4];
  const float* s0_bg   = (const float*)d_in[5];
  const float* s0_wb   = (const float*)d_in[6];
  const float* s0_bb   = (const float*)d_in[7];
  const float* s1_ws   = (const float*)d_in[8];
  const float* s1_bs   = (const float*)d_in[9];
  const float* s1_wg   = (const float*)d_in[10];
  const float* s1_bg   = (const float*)d_in[11];
  const float* s1_wb   = (const float*)d_in[12];
  const float* s1_bb   = (const float*)d_in[13];
  const float* conv0_w = (const float*)d_in[14];
  const float* conv0_b = (const float*)d_in[15];
  const float* conv1_w = (const float*)d_in[16];
  const float* conv1_b = (const float*)d_in[17];
  const float* convs_w = (const float*)d_in[18];

  float* out = (float*)d_out;
  char* ws = (char*)d_ws;
  short* xt    = (short*)(ws);               // [4][S3][64] bf16  16.78 MB
  short* actvT = (short*)(ws + 16777216);    // [4][S3][64]       16.78 MB
  short* hT    = (short*)(ws + 33554432);    // [4][S3][<=64]     16.78 MB
  short* d0T   = (short*)(ws + 50331648);    // [4][S3][32]        8.39 MB
  short* Wa0   = (short*)(ws + 58720256);
  short* Ws0   = (short*)(ws + 60817408);
  short* Wc0   = (short*)(ws + 62914560);
  short* Wa1   = (short*)(ws + 65011712);
  short* Ws1   = (short*)(ws + 67108864);
  short* Wc1   = (short*)(ws + 69206016);
  short* zp    = (short*)(ws + 70254592);    // 4KB zero page
  float* stats = (float*)(ws + 71303168);
  float* mu0 = stats, *rstd0 = stats + 256, *mu1 = stats + 512, *rstd1 = stats + 640;
  float* spart = stats + 1024;               // [4][64][64] partials

  hipMemsetAsync(zp, 0, 4096, stream);

  transpose_x<<<dim3(512, 4), 256, 0, stream>>>(x, xt);
  stats_kernel<<<dim3(256), 256, 0, stream>>>(x, mu0, rstd0);

  // weight repacks (per-b class selected) -> [b][27][KCH][CO2][16]
  repack_w<<<dim3(432, 4), 256, 0, stream>>>(s0_ws, nullptr, Wa0, y, 64, 64, 64,
                                             64L * 64 * 27, 0, 0, 110592);
  repack_w<<<dim3(864, 4), 256, 0, stream>>>(s0_wg, s0_wb, Ws0, y, 64, 128, 64,
                                             64L * 64 * 27, 64L * 64 * 27, 1, 221184);
  repack_w<<<dim3(216, 4), 256, 0, stream>>>(conv0_w, nullptr, Wc0, y, 32, 32, 64,
                                             0, 0, 0, 55296);
  repack_w<<<dim3(216, 4), 256, 0, stream>>>(s1_ws, nullptr, Wa1, y, 64, 64, 32,
                                             64L * 32 * 27, 0, 0, 55296);
  repack_w<<<dim3(432, 4), 256, 0, stream>>>(s1_wg, s1_wb, Ws1, y, 64, 64, 64,
                                             32L * 64 * 27, 32L * 64 * 27, 1, 110592);
  repack_w<<<dim3(108, 4), 256, 0, stream>>>(conv1_w, nullptr, Wc1, y, 32, 32, 32,
                                             0, 0, 0, 27648);

  // actv0 = relu(conv3(x, s0_ws) + s0_bs)          [B][S3][64]
  conv_mfma<64, 64, 64, 0, 0><<<dim3(128, 4, 1), 256, 0, stream>>>(
      xt, Wa0, s0_bs, 64, y, nullptr, nullptr, nullptr, nullptr, nullptr, zp,
      nullptr, actvT);
  // h0 = lrelu(SPADE0(x; actv0))                   [B][S3][64]
  conv_mfma<64, 64, 128, 2, 64><<<dim3(128, 4, 2), 256, 0, stream>>>(
      actvT, Ws0, nullptr, 0, y, xt, mu0, rstd0, s0_bg, s0_bb, zp,
      nullptr, hT);
  // dx0 = conv3(h0, conv0_w) + conv0_b             [B][S3][32]
  conv_mfma<64, 32, 32, 1, 0><<<dim3(128, 4, 1), 256, 0, stream>>>(
      hT, Wc0, conv0_b, 0, y, nullptr, nullptr, nullptr, nullptr, nullptr, zp,
      nullptr, d0T);
  // instance-norm stats of dx0 (two-phase)
  stats_t32_p1<<<dim3(64, 4), 256, 0, stream>>>(d0T, spart);
  stats_t32_p2<<<dim3(1), 128, 0, stream>>>(spart, mu1, rstd1);
  // actv1 = relu(conv3(dx0, s1_ws) + s1_bs)        [B][S3][64]
  conv_mfma<32, 64, 64, 0, 0><<<dim3(128, 4, 1), 256, 0, stream>>>(
      d0T, Wa1, s1_bs, 64, y, nullptr, nullptr, nullptr, nullptr, nullptr, zp,
      nullptr, actvT);
  // h1 = lrelu(SPADE1(dx0; actv1))                 [B][S3][32]
  conv_mfma<64, 64, 64, 2, 32><<<dim3(128, 4, 1), 256, 0, stream>>>(
      actvT, Ws1, nullptr, 0, y, d0T, mu1, rstd1, s1_bg, s1_bb, zp,
      nullptr, hT);
  // out = conv1x1(x, convs_w)
  shortcut_kernel<<<dim3(128, 4), 256, 0, stream>>>(x, convs_w, out);
  // out += conv3(h1, conv1_w) + conv1_b
  conv_mfma<32, 32, 32, 4, 0><<<dim3(128, 4, 1), 256, 0, stream>>>(
      hT, Wc1, conv1_b, 0, y, nullptr, nullptr, nullptr, nullptr, nullptr, zp,
      out, nullptr);
}

// Round 9
// 292.910 us; speedup vs baseline: 2.3590x; 1.0303x over previous
//
#include <hip/hip_runtime.h>

// SPADE ResNet block — bf16 MFMA implicit-GEMM, 32x32x16 MFMA.
// R9: LDS bank-conflict fix. All LDS buffers use a 16B-granule XOR swizzle
// swz(g) = g ^ ((g>>3)&7) applied BOTH sides (global_load_lds writes linear,
// so the staging source is pre-permuted; reads XOR the granule index).
// Plus s_setprio(1) around the MFMA cluster (T5; staging/compute role split).

#define S3 32768
constexpr float EPS = 1e-5f;

typedef __attribute__((ext_vector_type(8))) short s16x8;
typedef __attribute__((ext_vector_type(4))) float f32x4;
typedef __attribute__((ext_vector_type(16))) float f32x16;
typedef __attribute__((ext_vector_type(4))) unsigned short u16x4;
typedef __attribute__((ext_vector_type(8))) unsigned short u16x8;

#define GLL(g, l)                                                        \
  __builtin_amdgcn_global_load_lds(                                      \
      (const __attribute__((address_space(1))) void*)(g),                \
      (__attribute__((address_space(3))) void*)(l), 16, 0, 0)

__device__ __forceinline__ int swz(int g) { return g ^ ((g >> 3) & 7); }

__device__ __forceinline__ float bf2f(unsigned short u) {
  union { unsigned int i; float f; } v; v.i = ((unsigned int)u) << 16; return v.f;
}
__device__ __forceinline__ unsigned short f2bf(float f) {
  union { float f; unsigned int i; } v; v.f = f;
  unsigned int r = (v.i + 0x7FFFu + ((v.i >> 16) & 1u)) >> 16;
  return (unsigned short)r;
}

// ---------------------------------------------------------------- stats ----
__global__ __launch_bounds__(256) void stats_kernel(const float* __restrict__ x,
                                                    float* __restrict__ mu,
                                                    float* __restrict__ rstd) {
  const int bc = blockIdx.x;
  const float* p = x + (size_t)bc * S3;
  float s = 0.f, s2 = 0.f;
  for (int i = threadIdx.x; i < S3 / 4; i += 256) {
    float4 v = reinterpret_cast<const float4*>(p)[i];
    s  += v.x + v.y + v.z + v.w;
    s2 += v.x * v.x + v.y * v.y + v.z * v.z + v.w * v.w;
  }
  for (int off = 32; off; off >>= 1) {
    s  += __shfl_down(s, off, 64);
    s2 += __shfl_down(s2, off, 64);
  }
  __shared__ float ls[4], ls2[4];
  const int wid = threadIdx.x >> 6;
  if ((threadIdx.x & 63) == 0) { ls[wid] = s; ls2[wid] = s2; }
  __syncthreads();
  if (threadIdx.x == 0) {
    float S = 0.f, S2 = 0.f;
    for (int i = 0; i < 4; ++i) { S += ls[i]; S2 += ls2[i]; }
    const float m = S / (float)S3;
    const float var = S2 / (float)S3 - m * m;
    mu[bc] = m;
    rstd[bc] = rsqrtf(var + EPS);
  }
}

// Stats over bf16 T-layout tensor [B][S3][32] (dx0), phase 1.
__global__ __launch_bounds__(256) void stats_t32_p1(const short* __restrict__ t,
                                                    float* __restrict__ part) {
  const int b = blockIdx.y;
  const int chunk = blockIdx.x;
  const int tid = threadIdx.x;
  const int pq = tid & 3;
  float s[8], s2[8];
#pragma unroll
  for (int j = 0; j < 8; ++j) { s[j] = 0.f; s2[j] = 0.f; }
  const int vbase = chunk * 512;
#pragma unroll
  for (int v = tid >> 2; v < 512; v += 64) {
    u16x8 u = *reinterpret_cast<const u16x8*>(
        &t[((size_t)b * S3 + vbase + v) * 32 + pq * 8]);
#pragma unroll
    for (int j = 0; j < 8; ++j) { float f = bf2f(u[j]); s[j] += f; s2[j] += f * f; }
  }
#pragma unroll
  for (int off = 4; off < 64; off <<= 1) {
#pragma unroll
    for (int j = 0; j < 8; ++j) {
      s[j]  += __shfl_xor(s[j], off, 64);
      s2[j] += __shfl_xor(s2[j], off, 64);
    }
  }
  __shared__ float red[4][4][16];
  const int wv = tid >> 6, lane = tid & 63;
  if (lane < 4) {
#pragma unroll
    for (int j = 0; j < 8; ++j) { red[wv][lane][j] = s[j]; red[wv][lane][8 + j] = s2[j]; }
  }
  __syncthreads();
  if (tid < 32) {
    const int p = tid >> 3, j = tid & 7;
    float S = 0.f, S2 = 0.f;
#pragma unroll
    for (int w = 0; w < 4; ++w) { S += red[w][p][j]; S2 += red[w][p][8 + j]; }
    const int c = p * 8 + j;
    part[((size_t)(b * 64 + chunk)) * 64 + c] = S;
    part[((size_t)(b * 64 + chunk)) * 64 + 32 + c] = S2;
  }
}

__global__ __launch_bounds__(128) void stats_t32_p2(const float* __restrict__ part,
                                                    float* __restrict__ mu,
                                                    float* __restrict__ rstd) {
  const int tid = threadIdx.x;
  const int b = tid >> 5, c = tid & 31;
  float S = 0.f, S2 = 0.f;
#pragma unroll 4
  for (int k = 0; k < 64; ++k) {
    S  += part[((size_t)(b * 64 + k)) * 64 + c];
    S2 += part[((size_t)(b * 64 + k)) * 64 + 32 + c];
  }
  const float m = S / (float)S3;
  const float var = S2 / (float)S3 - m * m;
  mu[b * 32 + c] = m;
  rstd[b * 32 + c] = rsqrtf(var + EPS);
}

// ------------------------------------------------------------ transpose ----
__global__ __launch_bounds__(256) void transpose_x(const float* __restrict__ x,
                                                   short* __restrict__ xt) {
  const int b = blockIdx.y;
  const int v0 = blockIdx.x * 64;
  __shared__ unsigned short t[64][72];
  const int vox = threadIdx.x & 63;
  const int cg = threadIdx.x >> 6;
#pragma unroll
  for (int k = 0; k < 16; ++k) {
    const int ci = cg * 16 + k;
    t[vox][ci] = f2bf(x[((size_t)(b * 64 + ci)) * S3 + v0 + vox]);
  }
  __syncthreads();
  const int vv = threadIdx.x >> 2, part = threadIdx.x & 3;
  uint4 u0 = *reinterpret_cast<const uint4*>(&t[vv][part * 16]);
  uint4 u1 = *reinterpret_cast<const uint4*>(&t[vv][part * 16 + 8]);
  short* dst = &xt[((size_t)(b * S3 + v0 + vv)) * 64 + part * 16];
  *reinterpret_cast<uint4*>(dst) = u0;
  *reinterpret_cast<uint4*>(dst + 8) = u1;
}

// --------------------------------------------------------------- repack ----
// fp32 [cls][CO_src][CI][27] -> bf16 [b][27][KCH=CI/16][CO2][16ci].
__global__ __launch_bounds__(256) void repack_w(
    const float* __restrict__ wA, const float* __restrict__ wB,
    short* __restrict__ dst, const int* __restrict__ y,
    int CBLK, int CO2, int CI, long clsA, long clsB, int paired, int total) {
  const int b = blockIdx.y;
  const int idx = blockIdx.x * 256 + threadIdx.x;
  if (idx >= total) return;
  const int cls = y[b];
  const int KCH = CI / 16;
  const int ci = idx & 15;
  const int co = (idx >> 4) % CO2;
  const int rest = idx / (16 * CO2);
  const int k16 = rest % KCH;
  const int tap = rest / KCH;
  const int srcch = k16 * 16 + ci;
  float v;
  if (paired) {
    const int H = CBLK >> 1;
    const int blk = co / CBLK, w = co % CBLK;
    if (w < H)
      v = wA[(size_t)clsA * cls + ((size_t)(blk * H + w) * CI + srcch) * 27 + tap];
    else
      v = wB[(size_t)clsB * cls + ((size_t)(blk * H + w - H) * CI + srcch) * 27 + tap];
  } else {
    v = wA[(size_t)clsA * cls + ((size_t)co * CI + srcch) * 27 + tap];
  }
  dst[(((size_t)(b * 27 + tap) * KCH + k16) * CO2 + co) * 16 + ci] = (short)f2bf(v);
}

// ------------------------------------------------------------ conv MFMA ----
// 4x8x8 tile (256 vox), 4 waves (wave = d-slice, 64co x 64vox), CBLK co.
// Double-buffered X/W, one barrier per phase, XOR-swizzled LDS (both sides).
// EPI: 0 relu+bias->bf16T  1 bias->bf16T  2 SPADE+lrelu->bf16T  4 +=fp32
template <int CIN, int CBLK, int COTOT, int EPI, int NNORM>
__global__ __launch_bounds__(256, 2) void conv_mfma(
    const short* __restrict__ xt,      // [B][S3][CIN] bf16
    const short* __restrict__ W,       // [B][27][KCH][COTOT][16] bf16
    const float* __restrict__ bias,
    int bias_stride,
    const int* __restrict__ y,
    const short* __restrict__ xnb,     // EPI2: bf16 T [B][S3][NNORM]
    const float* __restrict__ mu,
    const float* __restrict__ rstd,
    const float* __restrict__ bgs,     // [NCLS][NNORM]
    const float* __restrict__ bbs,
    const short* __restrict__ zp,      // 4KB zero page
    float* __restrict__ outf,          // EPI4
    short* __restrict__ outb) {        // EPI 0..2
  constexpr int KCH = CIN / 16;
  constexpr int NCOG = CBLK / 32;
  constexpr int WCH = 9 * CBLK * 2;    // weight 16B granules per phase
  constexpr int WSH = (CBLK == 64) ? 6 : 5;

  __shared__ short ldsX[2][1200 * 8];  // [600 halo slots][2 halves][8 shorts]
  __shared__ short ldsW[2][WCH * 8];   // [9 taps][CBLK co][2 halves][8 shorts]

  const int tid = threadIdx.x;
  const int lane = tid & 63, wid = tid >> 6;
  const int l31 = lane & 31, khf = lane >> 5;
  const int b = blockIdx.y;
  const int cls = y[b];
  const int co_base = blockIdx.z * CBLK;
  const int tile = blockIdx.x;
  const int d0 = (tile >> 4) * 4, h0 = ((tile >> 2) & 3) * 8, w0 = (tile & 3) * 8;

  // X staging sources, pre-swizzled: LDS granule i holds logical granule swz(i).
  const short* gsrc[5];
#pragma unroll
  for (int k = 0; k < 5; ++k) {
    const int i = tid + k * 256;
    const short* g = zp;
    if (i < 1200) {
      const int lg = swz(i);           // logical granule
      const int slot = lg >> 1, half = lg & 1;
      const int sd = slot / 100, r0 = slot - sd * 100;
      const int sh = r0 / 10, sw0 = r0 - sh * 10;
      const int gd = d0 + sd - 1, gh = h0 + sh - 1, gw = w0 + sw0 - 1;
      if ((unsigned)gd < 32u && (unsigned)gh < 32u && (unsigned)gw < 32u)
        g = xt + ((size_t)b * S3 + gd * 1024 + gh * 32 + gw) * CIN + half * 8;
    }
    gsrc[k] = g;
  }

  auto stage_x = [&](int kc, int xb) {
#pragma unroll
    for (int k = 0; k < 5; ++k) {
      const int i = tid + k * 256;
      if (i < 1200) GLL(gsrc[k] + kc * 16, &ldsX[xb][i * 8]);
    }
  };
  auto stage_w = [&](int kc, int kd, int wb) {
#pragma unroll
    for (int k = 0; k < (WCH + 255) / 256; ++k) {
      const int i = tid + k * 256;
      if (i < WCH) {
        const int lg = swz(i);
        const int row = lg >> 1, half = lg & 1;
        const int t9 = row >> WSH, co = row & (CBLK - 1);
        GLL(W + (((size_t)(b * 27 + kd * 9 + t9) * KCH + kc) * COTOT +
                 co_base + co) * 16 + half * 8,
            &ldsW[wb][i * 8]);
      }
    }
  };

  f32x16 acc[2][NCOG];
#pragma unroll
  for (int v = 0; v < 2; ++v)
#pragma unroll
    for (int c = 0; c < NCOG; ++c)
#pragma unroll
      for (int r = 0; r < 16; ++r) acc[v][c][r] = 0.f;

  const int hw10 = (l31 >> 3) * 10 + (l31 & 7);   // lane's h*10+w offset

  stage_x(0, 0);
  stage_w(0, 0, 0);
  __syncthreads();

  int xb = 0;
#pragma unroll
  for (int ph = 0; ph < KCH * 3; ++ph) {
    const int kd = ph % 3;
    const int wb = ph & 1;
    if (ph + 1 < KCH * 3) {               // prefetch next phase
      const int nkc = (ph + 1) / 3, nkd = (ph + 1) % 3;
      stage_w(nkc, nkd, wb ^ 1);
      if (nkd == 0) stage_x(nkc, xb ^ 1);
    }
    __builtin_amdgcn_s_setprio(1);
#pragma unroll
    for (int kh = 0; kh < 3; ++kh) {
#pragma unroll
      for (int kw = 0; kw < 3; ++kw) {
        s16x8 af[NCOG];
#pragma unroll
        for (int c = 0; c < NCOG; ++c) {
          const int g = ((kh * 3 + kw) * CBLK + c * 32 + l31) * 2 + khf;
          af[c] = *reinterpret_cast<const s16x8*>(&ldsW[wb][swz(g) * 8]);
        }
        s16x8 bf[2];
#pragma unroll
        for (int vg = 0; vg < 2; ++vg) {
          const int slot = (wid + kd) * 100 + (vg * 4 + kh) * 10 + kw + hw10;
          const int g = slot * 2 + khf;
          bf[vg] = *reinterpret_cast<const s16x8*>(&ldsX[xb][swz(g) * 8]);
        }
#pragma unroll
        for (int c = 0; c < NCOG; ++c)
#pragma unroll
          for (int vg = 0; vg < 2; ++vg)
            acc[vg][c] = __builtin_amdgcn_mfma_f32_32x32x16_bf16(
                af[c], bf[vg], acc[vg][c], 0, 0, 0);
      }
    }
    __builtin_amdgcn_s_setprio(0);
    __syncthreads();
    if (kd == 2) xb ^= 1;
  }

  // epilogue. C: col = lane&31 -> voxel, row = (reg&3)+8*(reg>>2)+4*khf -> co.
  const int dgv = (d0 + wid) * 1024 + (h0 + (l31 >> 3)) * 32 + w0 + (l31 & 7);
  // vg adds vg*4 rows of h -> +vg*128

  if constexpr (EPI == 0 || EPI == 1) {
#pragma unroll
    for (int c = 0; c < NCOG; ++c)
#pragma unroll
      for (int q = 0; q < 4; ++q) {
        const int c0 = co_base + c * 32 + q * 8 + khf * 4;
        const f32x4 b4 = *reinterpret_cast<const f32x4*>(&bias[cls * bias_stride + c0]);
#pragma unroll
        for (int vg = 0; vg < 2; ++vg) {
          const int gv = dgv + vg * 128;
          u16x4 o;
#pragma unroll
          for (int rr = 0; rr < 4; ++rr) {
            float v = acc[vg][c][q * 4 + rr] + b4[rr];
            if constexpr (EPI == 0) v = fmaxf(v, 0.f);
            o[rr] = f2bf(v);
          }
          *reinterpret_cast<u16x4*>(&outb[((size_t)b * S3 + gv) * COTOT + c0]) = o;
        }
      }
  }

  if constexpr (EPI == 2) {
    const int nb = blockIdx.z * 32;      // gamma = acc[.][0], beta = acc[.][1]
#pragma unroll
    for (int q = 0; q < 4; ++q) {
      const int c0 = nb + q * 8 + khf * 4;
      const f32x4 m4  = *reinterpret_cast<const f32x4*>(&mu[b * NNORM + c0]);
      const f32x4 r4  = *reinterpret_cast<const f32x4*>(&rstd[b * NNORM + c0]);
      const f32x4 g4  = *reinterpret_cast<const f32x4*>(&bgs[cls * NNORM + c0]);
      const f32x4 bb4 = *reinterpret_cast<const f32x4*>(&bbs[cls * NNORM + c0]);
#pragma unroll
      for (int vg = 0; vg < 2; ++vg) {
        const int gv = dgv + vg * 128;
        const size_t vgl = (size_t)b * S3 + gv;
        u16x4 u = *reinterpret_cast<const u16x4*>(&xnb[vgl * NNORM + c0]);
        u16x4 o;
#pragma unroll
        for (int rr = 0; rr < 4; ++rr) {
          const float gamma = acc[vg][0][q * 4 + rr] + g4[rr];
          const float beta  = acc[vg][1][q * 4 + rr] + bb4[rr];
          const float nrm = (bf2f(u[rr]) - m4[rr]) * r4[rr];
          float h = nrm * (1.f + gamma) + beta;
          h = h > 0.f ? h : 0.2f * h;
          o[rr] = f2bf(h);
        }
        *reinterpret_cast<u16x4*>(&outb[vgl * NNORM + c0]) = o;
      }
    }
  }

  if constexpr (EPI == 4) {
#pragma unroll
    for (int q = 0; q < 4; ++q) {
      const int c0 = q * 8 + khf * 4;
      const f32x4 b4 = *reinterpret_cast<const f32x4*>(&bias[c0]);
#pragma unroll
      for (int vg = 0; vg < 2; ++vg) {
        const int gv = dgv + vg * 128;
#pragma unroll
        for (int rr = 0; rr < 4; ++rr) {
          float* p = &outf[((size_t)(b * 32 + c0 + rr)) * S3 + gv];
          *p += acc[vg][0][q * 4 + rr] + b4[rr];
        }
      }
    }
  }
}

// ------------------------------------------------------------- shortcut ----
__global__ __launch_bounds__(256) void shortcut_kernel(const float* __restrict__ x,
                                                       const float* __restrict__ wsc,
                                                       float* __restrict__ out) {
  const int b = blockIdx.y;
  const int v = blockIdx.x * 256 + threadIdx.x;
  __shared__ float lw[64 * 32];  // [ci][oc]
  for (int i = threadIdx.x; i < 2048; i += 256) {
    int ci = i >> 5, o = i & 31;
    lw[i] = wsc[o * 64 + ci];
  }
  __syncthreads();
  float acc[32];
#pragma unroll
  for (int o = 0; o < 32; ++o) acc[o] = 0.f;
  const float* xp = x + (size_t)b * 64 * S3 + v;
#pragma unroll 1
  for (int ci = 0; ci < 64; ++ci) {
    const float xv = xp[(size_t)ci * S3];
    const float4* wp = reinterpret_cast<const float4*>(&lw[ci << 5]);
#pragma unroll
    for (int o4 = 0; o4 < 8; ++o4) {
      float4 w4 = wp[o4];
      acc[o4 * 4 + 0] += xv * w4.x;
      acc[o4 * 4 + 1] += xv * w4.y;
      acc[o4 * 4 + 2] += xv * w4.z;
      acc[o4 * 4 + 3] += xv * w4.w;
    }
  }
  float* op = out + (size_t)b * 32 * S3 + v;
#pragma unroll
  for (int o = 0; o < 32; ++o) op[(size_t)o * S3] = acc[o];
}

// ---------------------------------------------------------------- launch ---
extern "C" void kernel_launch(void* const* d_in, const int* in_sizes, int n_in,
                              void* d_out, int out_size, void* d_ws, size_t ws_size,
                              hipStream_t stream) {
  const float* x       = (const float*)d_in[0];
  const int*   y       = (const int*)d_in[1];
  const float* s0_ws   = (const float*)d_in[2];
  const float* s0_bs   = (const float*)d_in[3];
  const float* s0_wg   = (const float*)d_in[4];
  const float* s0_bg   = (const float*)d_in[5];
  const float* s0_wb   = (const float*)d_in[6];
  const float* s0_bb   = (const float*)d_in[7];
  const float* s1_ws   = (const float*)d_in[8];
  const float* s1_bs   = (const float*)d_in[9];
  const float* s1_wg   = (const float*)d_in[10];
  const float* s1_bg   = (const float*)d_in[11];
  const float* s1_wb   = (const float*)d_in[12];
  const float* s1_bb   = (const float*)d_in[13];
  const float* conv0_w = (const float*)d_in[14];
  const float* conv0_b = (const float*)d_in[15];
  const float* conv1_w = (const float*)d_in[16];
  const float* conv1_b = (const float*)d_in[17];
  const float* convs_w = (const float*)d_in[18];

  float* out = (float*)d_out;
  char* ws = (char*)d_ws;
  short* xt    = (short*)(ws);               // [4][S3][64] bf16  16.78 MB
  short* actvT = (short*)(ws + 16777216);    // [4][S3][64]       16.78 MB
  short* hT    = (short*)(ws + 33554432);    // [4][S3][<=64]     16.78 MB
  short* d0T   = (short*)(ws + 50331648);    // [4][S3][32]        8.39 MB
  short* Wa0   = (short*)(ws + 58720256);
  short* Ws0   = (short*)(ws + 60817408);
  short* Wc0   = (short*)(ws + 62914560);
  short* Wa1   = (short*)(ws + 65011712);
  short* Ws1   = (short*)(ws + 67108864);
  short* Wc1   = (short*)(ws + 69206016);
  short* zp    = (short*)(ws + 70254592);    // 4KB zero page
  float* stats = (float*)(ws + 71303168);
  float* mu0 = stats, *rstd0 = stats + 256, *mu1 = stats + 512, *rstd1 = stats + 640;
  float* spart = stats + 1024;               // [4][64][64] partials

  hipMemsetAsync(zp, 0, 4096, stream);

  transpose_x<<<dim3(512, 4), 256, 0, stream>>>(x, xt);
  stats_kernel<<<dim3(256), 256, 0, stream>>>(x, mu0, rstd0);

  // weight repacks (per-b class selected) -> [b][27][KCH][CO2][16]
  repack_w<<<dim3(432, 4), 256, 0, stream>>>(s0_ws, nullptr, Wa0, y, 64, 64, 64,
                                             64L * 64 * 27, 0, 0, 110592);
  repack_w<<<dim3(864, 4), 256, 0, stream>>>(s0_wg, s0_wb, Ws0, y, 64, 128, 64,
                                             64L * 64 * 27, 64L * 64 * 27, 1, 221184);
  repack_w<<<dim3(216, 4), 256, 0, stream>>>(conv0_w, nullptr, Wc0, y, 32, 32, 64,
                                             0, 0, 0, 55296);
  repack_w<<<dim3(216, 4), 256, 0, stream>>>(s1_ws, nullptr, Wa1, y, 64, 64, 32,
                                             64L * 32 * 27, 0, 0, 55296);
  repack_w<<<dim3(432, 4), 256, 0, stream>>>(s1_wg, s1_wb, Ws1, y, 64, 64, 64,
                                             32L * 64 * 27, 32L * 64 * 27, 1, 110592);
  repack_w<<<dim3(108, 4), 256, 0, stream>>>(conv1_w, nullptr, Wc1, y, 32, 32, 32,
                                             0, 0, 0, 27648);

  // actv0 = relu(conv3(x, s0_ws) + s0_bs)          [B][S3][64]
  conv_mfma<64, 64, 64, 0, 0><<<dim3(128, 4, 1), 256, 0, stream>>>(
      xt, Wa0, s0_bs, 64, y, nullptr, nullptr, nullptr, nullptr, nullptr, zp,
      nullptr, actvT);
  // h0 = lrelu(SPADE0(x; actv0))                   [B][S3][64]
  conv_mfma<64, 64, 128, 2, 64><<<dim3(128, 4, 2), 256, 0, stream>>>(
      actvT, Ws0, nullptr, 0, y, xt, mu0, rstd0, s0_bg, s0_bb, zp,
      nullptr, hT);
  // dx0 = conv3(h0, conv0_w) + conv0_b             [B][S3][32]
  conv_mfma<64, 32, 32, 1, 0><<<dim3(128, 4, 1), 256, 0, stream>>>(
      hT, Wc0, conv0_b, 0, y, nullptr, nullptr, nullptr, nullptr, nullptr, zp,
      nullptr, d0T);
  // instance-norm stats of dx0 (two-phase)
  stats_t32_p1<<<dim3(64, 4), 256, 0, stream>>>(d0T, spart);
  stats_t32_p2<<<dim3(1), 128, 0, stream>>>(spart, mu1, rstd1);
  // actv1 = relu(conv3(dx0, s1_ws) + s1_bs)        [B][S3][64]
  conv_mfma<32, 64, 64, 0, 0><<<dim3(128, 4, 1), 256, 0, stream>>>(
      d0T, Wa1, s1_bs, 64, y, nullptr, nullptr, nullptr, nullptr, nullptr, zp,
      nullptr, actvT);
  // h1 = lrelu(SPADE1(dx0; actv1))                 [B][S3][32]
  conv_mfma<64, 64, 64, 2, 32><<<dim3(128, 4, 1), 256, 0, stream>>>(
      actvT, Ws1, nullptr, 0, y, d0T, mu1, rstd1, s1_bg, s1_bb, zp,
      nullptr, hT);
  // out = conv1x1(x, convs_w)
  shortcut_kernel<<<dim3(128, 4), 256, 0, stream>>>(x, convs_w, out);
  // out += conv3(h1, conv1_w) + conv1_b
  conv_mfma<32, 32, 32, 4, 0><<<dim3(128, 4, 1), 256, 0, stream>>>(
      hT, Wc1, conv1_b, 0, y, nullptr, nullptr, nullptr, nullptr, nullptr, zp,
      out, nullptr);
}

// Round 10
// 287.695 us; speedup vs baseline: 2.4018x; 1.0181x over previous
//
#include <hip/hip_runtime.h>

// SPADE ResNet block — bf16 MFMA implicit-GEMM, 32x32x16 MFMA.
// R10: bank-conflict fix by LAYOUT (R9's XOR swizzle didn't match the
// pattern). X in LDS = two khf planes (16B/slot each, plane stride == 64
// mod 128 B) -> bf reads hit all 8 bank-quads evenly (2/quad per 16-lane
// phase = b128 floor). W in LDS reordered to lane order (khf*32+co) -> af
// reads are contiguous 1KB. global_load_lds stays linear-dest; the per-lane
// GLOBAL source encodes the permutation.

#define S3 32768
constexpr float EPS = 1e-5f;

typedef __attribute__((ext_vector_type(8))) short s16x8;
typedef __attribute__((ext_vector_type(4))) float f32x4;
typedef __attribute__((ext_vector_type(16))) float f32x16;
typedef __attribute__((ext_vector_type(4))) unsigned short u16x4;
typedef __attribute__((ext_vector_type(8))) unsigned short u16x8;

#define GLL(g, l)                                                        \
  __builtin_amdgcn_global_load_lds(                                      \
      (const __attribute__((address_space(1))) void*)(g),                \
      (__attribute__((address_space(3))) void*)(l), 16, 0, 0)

__device__ __forceinline__ float bf2f(unsigned short u) {
  union { unsigned int i; float f; } v; v.i = ((unsigned int)u) << 16; return v.f;
}
__device__ __forceinline__ unsigned short f2bf(float f) {
  union { float f; unsigned int i; } v; v.f = f;
  unsigned int r = (v.i + 0x7FFFu + ((v.i >> 16) & 1u)) >> 16;
  return (unsigned short)r;
}

// ---------------------------------------------------------------- stats ----
__global__ __launch_bounds__(256) void stats_kernel(const float* __restrict__ x,
                                                    float* __restrict__ mu,
                                                    float* __restrict__ rstd) {
  const int bc = blockIdx.x;
  const float* p = x + (size_t)bc * S3;
  float s = 0.f, s2 = 0.f;
  for (int i = threadIdx.x; i < S3 / 4; i += 256) {
    float4 v = reinterpret_cast<const float4*>(p)[i];
    s  += v.x + v.y + v.z + v.w;
    s2 += v.x * v.x + v.y * v.y + v.z * v.z + v.w * v.w;
  }
  for (int off = 32; off; off >>= 1) {
    s  += __shfl_down(s, off, 64);
    s2 += __shfl_down(s2, off, 64);
  }
  __shared__ float ls[4], ls2[4];
  const int wid = threadIdx.x >> 6;
  if ((threadIdx.x & 63) == 0) { ls[wid] = s; ls2[wid] = s2; }
  __syncthreads();
  if (threadIdx.x == 0) {
    float S = 0.f, S2 = 0.f;
    for (int i = 0; i < 4; ++i) { S += ls[i]; S2 += ls2[i]; }
    const float m = S / (float)S3;
    const float var = S2 / (float)S3 - m * m;
    mu[bc] = m;
    rstd[bc] = rsqrtf(var + EPS);
  }
}

// Stats over bf16 T-layout tensor [B][S3][32] (dx0), phase 1.
__global__ __launch_bounds__(256) void stats_t32_p1(const short* __restrict__ t,
                                                    float* __restrict__ part) {
  const int b = blockIdx.y;
  const int chunk = blockIdx.x;
  const int tid = threadIdx.x;
  const int pq = tid & 3;
  float s[8], s2[8];
#pragma unroll
  for (int j = 0; j < 8; ++j) { s[j] = 0.f; s2[j] = 0.f; }
  const int vbase = chunk * 512;
#pragma unroll
  for (int v = tid >> 2; v < 512; v += 64) {
    u16x8 u = *reinterpret_cast<const u16x8*>(
        &t[((size_t)b * S3 + vbase + v) * 32 + pq * 8]);
#pragma unroll
    for (int j = 0; j < 8; ++j) { float f = bf2f(u[j]); s[j] += f; s2[j] += f * f; }
  }
#pragma unroll
  for (int off = 4; off < 64; off <<= 1) {
#pragma unroll
    for (int j = 0; j < 8; ++j) {
      s[j]  += __shfl_xor(s[j], off, 64);
      s2[j] += __shfl_xor(s2[j], off, 64);
    }
  }
  __shared__ float red[4][4][16];
  const int wv = tid >> 6, lane = tid & 63;
  if (lane < 4) {
#pragma unroll
    for (int j = 0; j < 8; ++j) { red[wv][lane][j] = s[j]; red[wv][lane][8 + j] = s2[j]; }
  }
  __syncthreads();
  if (tid < 32) {
    const int p = tid >> 3, j = tid & 7;
    float S = 0.f, S2 = 0.f;
#pragma unroll
    for (int w = 0; w < 4; ++w) { S += red[w][p][j]; S2 += red[w][p][8 + j]; }
    const int c = p * 8 + j;
    part[((size_t)(b * 64 + chunk)) * 64 + c] = S;
    part[((size_t)(b * 64 + chunk)) * 64 + 32 + c] = S2;
  }
}

__global__ __launch_bounds__(128) void stats_t32_p2(const float* __restrict__ part,
                                                    float* __restrict__ mu,
                                                    float* __restrict__ rstd) {
  const int tid = threadIdx.x;
  const int b = tid >> 5, c = tid & 31;
  float S = 0.f, S2 = 0.f;
#pragma unroll 4
  for (int k = 0; k < 64; ++k) {
    S  += part[((size_t)(b * 64 + k)) * 64 + c];
    S2 += part[((size_t)(b * 64 + k)) * 64 + 32 + c];
  }
  const float m = S / (float)S3;
  const float var = S2 / (float)S3 - m * m;
  mu[b * 32 + c] = m;
  rstd[b * 32 + c] = rsqrtf(var + EPS);
}

// ------------------------------------------------------------ transpose ----
__global__ __launch_bounds__(256) void transpose_x(const float* __restrict__ x,
                                                   short* __restrict__ xt) {
  const int b = blockIdx.y;
  const int v0 = blockIdx.x * 64;
  __shared__ unsigned short t[64][72];
  const int vox = threadIdx.x & 63;
  const int cg = threadIdx.x >> 6;
#pragma unroll
  for (int k = 0; k < 16; ++k) {
    const int ci = cg * 16 + k;
    t[vox][ci] = f2bf(x[((size_t)(b * 64 + ci)) * S3 + v0 + vox]);
  }
  __syncthreads();
  const int vv = threadIdx.x >> 2, part = threadIdx.x & 3;
  uint4 u0 = *reinterpret_cast<const uint4*>(&t[vv][part * 16]);
  uint4 u1 = *reinterpret_cast<const uint4*>(&t[vv][part * 16 + 8]);
  short* dst = &xt[((size_t)(b * S3 + v0 + vv)) * 64 + part * 16];
  *reinterpret_cast<uint4*>(dst) = u0;
  *reinterpret_cast<uint4*>(dst + 8) = u1;
}

// --------------------------------------------------------------- repack ----
// fp32 [cls][CO_src][CI][27] -> bf16 [b][27][KCH=CI/16][CO2][16ci].
__global__ __launch_bounds__(256) void repack_w(
    const float* __restrict__ wA, const float* __restrict__ wB,
    short* __restrict__ dst, const int* __restrict__ y,
    int CBLK, int CO2, int CI, long clsA, long clsB, int paired, int total) {
  const int b = blockIdx.y;
  const int idx = blockIdx.x * 256 + threadIdx.x;
  if (idx >= total) return;
  const int cls = y[b];
  const int KCH = CI / 16;
  const int ci = idx & 15;
  const int co = (idx >> 4) % CO2;
  const int rest = idx / (16 * CO2);
  const int k16 = rest % KCH;
  const int tap = rest / KCH;
  const int srcch = k16 * 16 + ci;
  float v;
  if (paired) {
    const int H = CBLK >> 1;
    const int blk = co / CBLK, w = co % CBLK;
    if (w < H)
      v = wA[(size_t)clsA * cls + ((size_t)(blk * H + w) * CI + srcch) * 27 + tap];
    else
      v = wB[(size_t)clsB * cls + ((size_t)(blk * H + w - H) * CI + srcch) * 27 + tap];
  } else {
    v = wA[(size_t)clsA * cls + ((size_t)co * CI + srcch) * 27 + tap];
  }
  dst[(((size_t)(b * 27 + tap) * KCH + k16) * CO2 + co) * 16 + ci] = (short)f2bf(v);
}

// ------------------------------------------------------------ conv MFMA ----
// 4x8x8 tile (256 vox), 4 waves (wave = d-slice, 64co x 64vox), CBLK co.
// Double-buffered X/W, one barrier per phase.
// LDS X: [khf plane (604 granules)][slot] ; LDS W: [tap][c][lane-order 64].
// EPI: 0 relu+bias->bf16T  1 bias->bf16T  2 SPADE+lrelu->bf16T  4 +=fp32
template <int CIN, int CBLK, int COTOT, int EPI, int NNORM>
__global__ __launch_bounds__(256, 2) void conv_mfma(
    const short* __restrict__ xt,      // [B][S3][CIN] bf16
    const short* __restrict__ W,       // [B][27][KCH][COTOT][16] bf16
    const float* __restrict__ bias,
    int bias_stride,
    const int* __restrict__ y,
    const short* __restrict__ xnb,     // EPI2: bf16 T [B][S3][NNORM]
    const float* __restrict__ mu,
    const float* __restrict__ rstd,
    const float* __restrict__ bgs,     // [NCLS][NNORM]
    const float* __restrict__ bbs,
    const short* __restrict__ zp,      // 4KB zero page
    float* __restrict__ outf,          // EPI4
    short* __restrict__ outb) {        // EPI 0..2
  constexpr int KCH = CIN / 16;
  constexpr int NCOG = CBLK / 32;
  constexpr int PG = 604;              // X plane stride in granules (==4 mod 8)
  constexpr int XG = 2 * PG;           // 1208 granules per X buffer
  constexpr int WG = 9 * NCOG * 64;    // W granules per phase chunk

  __shared__ short ldsX[2][XG * 8];
  __shared__ short ldsW[2][WG * 8];

  const int tid = threadIdx.x;
  const int lane = tid & 63, wid = tid >> 6;
  const int l31 = lane & 31, khf = lane >> 5;
  const int b = blockIdx.y;
  const int cls = y[b];
  const int co_base = blockIdx.z * CBLK;
  const int tile = blockIdx.x;
  const int d0 = (tile >> 4) * 4, h0 = ((tile >> 2) & 3) * 8, w0 = (tile & 3) * 8;

  // X staging sources: granule i -> (plane = i>=PG, slot = i - plane*PG),
  // source = voxel(slot) channels [kc*16 + plane*8, +8).
  const short* gsrc[5];
#pragma unroll
  for (int k = 0; k < 5; ++k) {
    const int i = tid + k * 256;
    const short* g = zp;
    if (i < XG) {
      const int pl = (i >= PG) ? 1 : 0;
      const int slot = i - pl * PG;
      if (slot < 600) {
        const int sd = slot / 100, r0 = slot - sd * 100;
        const int sh = r0 / 10, sw0 = r0 - sh * 10;
        const int gd = d0 + sd - 1, gh = h0 + sh - 1, gw = w0 + sw0 - 1;
        if ((unsigned)gd < 32u && (unsigned)gh < 32u && (unsigned)gw < 32u)
          g = xt + ((size_t)b * S3 + gd * 1024 + gh * 32 + gw) * CIN + pl * 8;
      }
    }
    gsrc[k] = g;
  }

  auto stage_x = [&](int kc, int xb) {
#pragma unroll
    for (int k = 0; k < 5; ++k) {
      const int i = tid + k * 256;
      if (i < XG) GLL(gsrc[k] + kc * 16, &ldsX[xb][i * 8]);
    }
  };
  // W staging: granule i -> tap t9 = i/(NCOG*64), c = (i%(NCOG*64))>>6,
  // q = i&63: lane-order q = khf*32 + co31.
  auto stage_w = [&](int kc, int kd, int wb) {
#pragma unroll
    for (int k = 0; k < (WG + 255) / 256; ++k) {
      const int i = tid + k * 256;
      if (i < WG) {
        const int t9 = i / (NCOG * 64);
        const int r = i - t9 * (NCOG * 64);
        const int c = r >> 6, q = r & 63;
        GLL(W + (((size_t)(b * 27 + kd * 9 + t9) * KCH + kc) * COTOT +
                 co_base + c * 32 + (q & 31)) * 16 + (q >> 5) * 8,
            &ldsW[wb][i * 8]);
      }
    }
  };

  f32x16 acc[2][NCOG];
#pragma unroll
  for (int v = 0; v < 2; ++v)
#pragma unroll
    for (int c = 0; c < NCOG; ++c)
#pragma unroll
      for (int r = 0; r < 16; ++r) acc[v][c][r] = 0.f;

  const int hw10 = (l31 >> 3) * 10 + (l31 & 7);   // lane's h*10+w offset
  const int xpl = khf * PG;                       // lane's X plane base (granules)

  stage_x(0, 0);
  stage_w(0, 0, 0);
  __syncthreads();

  int xb = 0;
#pragma unroll
  for (int ph = 0; ph < KCH * 3; ++ph) {
    const int kd = ph % 3;
    const int wb = ph & 1;
    if (ph + 1 < KCH * 3) {               // prefetch next phase
      const int nkc = (ph + 1) / 3, nkd = (ph + 1) % 3;
      stage_w(nkc, nkd, wb ^ 1);
      if (nkd == 0) stage_x(nkc, xb ^ 1);
    }
    __builtin_amdgcn_s_setprio(1);
#pragma unroll
    for (int kh = 0; kh < 3; ++kh) {
#pragma unroll
      for (int kw = 0; kw < 3; ++kw) {
        const int t9 = kh * 3 + kw;
        s16x8 af[NCOG];
#pragma unroll
        for (int c = 0; c < NCOG; ++c)
          af[c] = *reinterpret_cast<const s16x8*>(
              &ldsW[wb][((t9 * NCOG + c) * 64 + lane) * 8]);
        s16x8 bf[2];
#pragma unroll
        for (int vg = 0; vg < 2; ++vg) {
          const int slot = (wid + kd) * 100 + (vg * 4 + kh) * 10 + kw + hw10;
          bf[vg] = *reinterpret_cast<const s16x8*>(&ldsX[xb][(xpl + slot) * 8]);
        }
#pragma unroll
        for (int c = 0; c < NCOG; ++c)
#pragma unroll
          for (int vg = 0; vg < 2; ++vg)
            acc[vg][c] = __builtin_amdgcn_mfma_f32_32x32x16_bf16(
                af[c], bf[vg], acc[vg][c], 0, 0, 0);
      }
    }
    __builtin_amdgcn_s_setprio(0);
    __syncthreads();
    if (kd == 2) xb ^= 1;
  }

  // epilogue. C: col = lane&31 -> voxel, row = (reg&3)+8*(reg>>2)+4*khf -> co.
  const int dgv = (d0 + wid) * 1024 + (h0 + (l31 >> 3)) * 32 + w0 + (l31 & 7);
  // vg adds vg*4 rows of h -> +vg*128

  if constexpr (EPI == 0 || EPI == 1) {
#pragma unroll
    for (int c = 0; c < NCOG; ++c)
#pragma unroll
      for (int q = 0; q < 4; ++q) {
        const int c0 = co_base + c * 32 + q * 8 + khf * 4;
        const f32x4 b4 = *reinterpret_cast<const f32x4*>(&bias[cls * bias_stride + c0]);
#pragma unroll
        for (int vg = 0; vg < 2; ++vg) {
          const int gv = dgv + vg * 128;
          u16x4 o;
#pragma unroll
          for (int rr = 0; rr < 4; ++rr) {
            float v = acc[vg][c][q * 4 + rr] + b4[rr];
            if constexpr (EPI == 0) v = fmaxf(v, 0.f);
            o[rr] = f2bf(v);
          }
          *reinterpret_cast<u16x4*>(&outb[((size_t)b * S3 + gv) * COTOT + c0]) = o;
        }
      }
  }

  if constexpr (EPI == 2) {
    const int nb = blockIdx.z * 32;      // gamma = acc[.][0], beta = acc[.][1]
#pragma unroll
    for (int q = 0; q < 4; ++q) {
      const int c0 = nb + q * 8 + khf * 4;
      const f32x4 m4  = *reinterpret_cast<const f32x4*>(&mu[b * NNORM + c0]);
      const f32x4 r4  = *reinterpret_cast<const f32x4*>(&rstd[b * NNORM + c0]);
      const f32x4 g4  = *reinterpret_cast<const f32x4*>(&bgs[cls * NNORM + c0]);
      const f32x4 bb4 = *reinterpret_cast<const f32x4*>(&bbs[cls * NNORM + c0]);
#pragma unroll
      for (int vg = 0; vg < 2; ++vg) {
        const int gv = dgv + vg * 128;
        const size_t vgl = (size_t)b * S3 + gv;
        u16x4 u = *reinterpret_cast<const u16x4*>(&xnb[vgl * NNORM + c0]);
        u16x4 o;
#pragma unroll
        for (int rr = 0; rr < 4; ++rr) {
          const float gamma = acc[vg][0][q * 4 + rr] + g4[rr];
          const float beta  = acc[vg][1][q * 4 + rr] + bb4[rr];
          const float nrm = (bf2f(u[rr]) - m4[rr]) * r4[rr];
          float h = nrm * (1.f + gamma) + beta;
          h = h > 0.f ? h : 0.2f * h;
          o[rr] = f2bf(h);
        }
        *reinterpret_cast<u16x4*>(&outb[vgl * NNORM + c0]) = o;
      }
    }
  }

  if constexpr (EPI == 4) {
#pragma unroll
    for (int q = 0; q < 4; ++q) {
      const int c0 = q * 8 + khf * 4;
      const f32x4 b4 = *reinterpret_cast<const f32x4*>(&bias[c0]);
#pragma unroll
      for (int vg = 0; vg < 2; ++vg) {
        const int gv = dgv + vg * 128;
#pragma unroll
        for (int rr = 0; rr < 4; ++rr) {
          float* p = &outf[((size_t)(b * 32 + c0 + rr)) * S3 + gv];
          *p += acc[vg][0][q * 4 + rr] + b4[rr];
        }
      }
    }
  }
}

// ------------------------------------------------------------- shortcut ----
__global__ __launch_bounds__(256) void shortcut_kernel(const float* __restrict__ x,
                                                       const float* __restrict__ wsc,
                                                       float* __restrict__ out) {
  const int b = blockIdx.y;
  const int v = blockIdx.x * 256 + threadIdx.x;
  __shared__ float lw[64 * 32];  // [ci][oc]
  for (int i = threadIdx.x; i < 2048; i += 256) {
    int ci = i >> 5, o = i & 31;
    lw[i] = wsc[o * 64 + ci];
  }
  __syncthreads();
  float acc[32];
#pragma unroll
  for (int o = 0; o < 32; ++o) acc[o] = 0.f;
  const float* xp = x + (size_t)b * 64 * S3 + v;
#pragma unroll 1
  for (int ci = 0; ci < 64; ++ci) {
    const float xv = xp[(size_t)ci * S3];
    const float4* wp = reinterpret_cast<const float4*>(&lw[ci << 5]);
#pragma unroll
    for (int o4 = 0; o4 < 8; ++o4) {
      float4 w4 = wp[o4];
      acc[o4 * 4 + 0] += xv * w4.x;
      acc[o4 * 4 + 1] += xv * w4.y;
      acc[o4 * 4 + 2] += xv * w4.z;
      acc[o4 * 4 + 3] += xv * w4.w;
    }
  }
  float* op = out + (size_t)b * 32 * S3 + v;
#pragma unroll
  for (int o = 0; o < 32; ++o) op[(size_t)o * S3] = acc[o];
}

// ---------------------------------------------------------------- launch ---
extern "C" void kernel_launch(void* const* d_in, const int* in_sizes, int n_in,
                              void* d_out, int out_size, void* d_ws, size_t ws_size,
                              hipStream_t stream) {
  const float* x       = (const float*)d_in[0];
  const int*   y       = (const int*)d_in[1];
  const float* s0_ws   = (const float*)d_in[2];
  const float* s0_bs   = (const float*)d_in[3];
  const float* s0_wg   = (const float*)d_in[4];
  const float* s0_bg   = (const float*)d_in[5];
  const float* s0_wb   = (const float*)d_in[6];
  const float* s0_bb   = (const float*)d_in[7];
  const float* s1_ws   = (const float*)d_in[8];
  const float* s1_bs   = (const float*)d_in[9];
  const float* s1_wg   = (const float*)d_in[10];
  const float* s1_bg   = (const float*)d_in[11];
  const float* s1_wb   = (const float*)d_in[12];
  const float* s1_bb   = (const float*)d_in[13];
  const float* conv0_w = (const float*)d_in[14];
  const float* conv0_b = (const float*)d_in[15];
  const float* conv1_w = (const float*)d_in[16];
  const float* conv1_b = (const float*)d_in[17];
  const float* convs_w = (const float*)d_in[18];

  float* out = (float*)d_out;
  char* ws = (char*)d_ws;
  short* xt    = (short*)(ws);               // [4][S3][64] bf16  16.78 MB
  short* actvT = (short*)(ws + 16777216);    // [4][S3][64]       16.78 MB
  short* hT    = (short*)(ws + 33554432);    // [4][S3][<=64]     16.78 MB
  short* d0T   = (short*)(ws + 50331648);    // [4][S3][32]        8.39 MB
  short* Wa0   = (short*)(ws + 58720256);
  short* Ws0   = (short*)(ws + 60817408);
  short* Wc0   = (short*)(ws + 62914560);
  short* Wa1   = (short*)(ws + 65011712);
  short* Ws1   = (short*)(ws + 67108864);
  short* Wc1   = (short*)(ws + 69206016);
  short* zp    = (short*)(ws + 70254592);    // 4KB zero page
  float* stats = (float*)(ws + 71303168);
  float* mu0 = stats, *rstd0 = stats + 256, *mu1 = stats + 512, *rstd1 = stats + 640;
  float* spart = stats + 1024;               // [4][64][64] partials

  hipMemsetAsync(zp, 0, 4096, stream);

  transpose_x<<<dim3(512, 4), 256, 0, stream>>>(x, xt);
  stats_kernel<<<dim3(256), 256, 0, stream>>>(x, mu0, rstd0);

  // weight repacks (per-b class selected) -> [b][27][KCH][CO2][16]
  repack_w<<<dim3(432, 4), 256, 0, stream>>>(s0_ws, nullptr, Wa0, y, 64, 64, 64,
                                             64L * 64 * 27, 0, 0, 110592);
  repack_w<<<dim3(864, 4), 256, 0, stream>>>(s0_wg, s0_wb, Ws0, y, 64, 128, 64,
                                             64L * 64 * 27, 64L * 64 * 27, 1, 221184);
  repack_w<<<dim3(216, 4), 256, 0, stream>>>(conv0_w, nullptr, Wc0, y, 32, 32, 64,
                                             0, 0, 0, 55296);
  repack_w<<<dim3(216, 4), 256, 0, stream>>>(s1_ws, nullptr, Wa1, y, 64, 64, 32,
                                             64L * 32 * 27, 0, 0, 55296);
  repack_w<<<dim3(432, 4), 256, 0, stream>>>(s1_wg, s1_wb, Ws1, y, 64, 64, 64,
                                             32L * 64 * 27, 32L * 64 * 27, 1, 110592);
  repack_w<<<dim3(108, 4), 256, 0, stream>>>(conv1_w, nullptr, Wc1, y, 32, 32, 32,
                                             0, 0, 0, 27648);

  // actv0 = relu(conv3(x, s0_ws) + s0_bs)          [B][S3][64]
  conv_mfma<64, 64, 64, 0, 0><<<dim3(128, 4, 1), 256, 0, stream>>>(
      xt, Wa0, s0_bs, 64, y, nullptr, nullptr, nullptr, nullptr, nullptr, zp,
      nullptr, actvT);
  // h0 = lrelu(SPADE0(x; actv0))                   [B][S3][64]
  conv_mfma<64, 64, 128, 2, 64><<<dim3(128, 4, 2), 256, 0, stream>>>(
      actvT, Ws0, nullptr, 0, y, xt, mu0, rstd0, s0_bg, s0_bb, zp,
      nullptr, hT);
  // dx0 = conv3(h0, conv0_w) + conv0_b             [B][S3][32]
  conv_mfma<64, 32, 32, 1, 0><<<dim3(128, 4, 1), 256, 0, stream>>>(
      hT, Wc0, conv0_b, 0, y, nullptr, nullptr, nullptr, nullptr, nullptr, zp,
      nullptr, d0T);
  // instance-norm stats of dx0 (two-phase)
  stats_t32_p1<<<dim3(64, 4), 256, 0, stream>>>(d0T, spart);
  stats_t32_p2<<<dim3(1), 128, 0, stream>>>(spart, mu1, rstd1);
  // actv1 = relu(conv3(dx0, s1_ws) + s1_bs)        [B][S3][64]
  conv_mfma<32, 64, 64, 0, 0><<<dim3(128, 4, 1), 256, 0, stream>>>(
      d0T, Wa1, s1_bs, 64, y, nullptr, nullptr, nullptr, nullptr, nullptr, zp,
      nullptr, actvT);
  // h1 = lrelu(SPADE1(dx0; actv1))                 [B][S3][32]
  conv_mfma<64, 64, 64, 2, 32><<<dim3(128, 4, 1), 256, 0, stream>>>(
      actvT, Ws1, nullptr, 0, y, d0T, mu1, rstd1, s1_bg, s1_bb, zp,
      nullptr, hT);
  // out = conv1x1(x, convs_w)
  shortcut_kernel<<<dim3(128, 4), 256, 0, stream>>>(x, convs_w, out);
  // out += conv3(h1, conv1_w) + conv1_b
  conv_mfma<32, 32, 32, 4, 0><<<dim3(128, 4, 1), 256, 0, stream>>>(
      hT, Wc1, conv1_b, 0, y, nullptr, nullptr, nullptr, nullptr, nullptr, zp,
      out, nullptr);
}